// Round 1
// baseline (10611.677 us; speedup 1.0000x reference)
//
#include <hip/hip_runtime.h>
#include <hip/hip_cooperative_groups.h>
#include <math.h>

namespace cg = cooperative_groups;

#define B 64
#define P 196
#define E 2048
#define D 256
#define H_ 256
#define EM 256
#define V 10000
#define L 32
#define T 31
#define KX 2560   // EM + E + D

// ---------------- sort: stable argsort descending by length ----------------
__global__ __launch_bounds__(64) void sort_kernel(const int* __restrict__ clen,
                                                  int* __restrict__ order,
                                                  int* __restrict__ target) {
    __shared__ int len_s[B];
    int i = threadIdx.x;
    len_s[i] = clen[i];
    __syncthreads();
    int li = len_s[i];
    int rank = 0;
    for (int j = 0; j < B; ++j) {
        int lj = len_s[j];
        if (lj > li || (lj == li && j < i)) rank++;
    }
    order[rank] = i;
    target[rank] = li - 1;
}

// ---------------- mean_feat[b][e] = mean_p feat[src][p][e] ----------------
__global__ __launch_bounds__(256) void mean_kernel(const float* __restrict__ feat,
                                                   const int* __restrict__ order,
                                                   float* __restrict__ mean_feat) {
    int b = blockIdx.x;
    int e = blockIdx.y * 256 + threadIdx.x;
    int src = order[b];
    const float* fp = feat + (size_t)src * P * E + e;
    float acc = 0.f;
    #pragma unroll 4
    for (int p = 0; p < P; ++p) acc += fp[(size_t)p * E];
    mean_feat[b * E + e] = acc * (1.0f / (float)P);
}

// ---------------- h0c0 as split-K GEMM: hpart[ky][64][512] ----------------
__global__ __launch_bounds__(256) void h0c0_gemm(const float* __restrict__ mean_feat,
                                                 const float* __restrict__ W_hid,
                                                 const float* __restrict__ W_cell,
                                                 float* __restrict__ hpart) {
    __shared__ float As[32][68];
    __shared__ float Bs[32][64];
    int cb = blockIdx.x;   // 0..7
    int ky = blockIdx.y;   // 0..7
    int tid = threadIdx.x;
    int tx = tid & 15, ty = tid >> 4;
    const float* Wsrc;
    int ncol0;
    if (cb < 4) { Wsrc = W_hid;  ncol0 = cb * 64; }
    else        { Wsrc = W_cell; ncol0 = (cb - 4) * 64; }
    float acc[4][4] = {};
    for (int k0 = ky * 256; k0 < ky * 256 + 256; k0 += 32) {
        #pragma unroll
        for (int q = 0; q < 2; ++q) {
            int idx = q * 256 + tid;
            int kv = idx & 7, m = idx >> 3;
            float4 v = *(const float4*)(mean_feat + (size_t)m * E + k0 + kv * 4);
            As[kv * 4 + 0][m] = v.x;
            As[kv * 4 + 1][m] = v.y;
            As[kv * 4 + 2][m] = v.z;
            As[kv * 4 + 3][m] = v.w;
        }
        #pragma unroll
        for (int q = 0; q < 2; ++q) {
            int idx = q * 256 + tid;
            int n4 = idx & 15, kk = idx >> 4;
            float4 v = *(const float4*)(Wsrc + (size_t)(k0 + kk) * 256 + ncol0 + n4 * 4);
            *(float4*)&Bs[kk][n4 * 4] = v;
        }
        __syncthreads();
        #pragma unroll
        for (int kk = 0; kk < 32; ++kk) {
            float4 av = *(const float4*)&As[kk][ty * 4];
            float4 bv = *(const float4*)&Bs[kk][tx * 4];
            acc[0][0] += av.x * bv.x; acc[0][1] += av.x * bv.y; acc[0][2] += av.x * bv.z; acc[0][3] += av.x * bv.w;
            acc[1][0] += av.y * bv.x; acc[1][1] += av.y * bv.y; acc[1][2] += av.y * bv.z; acc[1][3] += av.y * bv.w;
            acc[2][0] += av.z * bv.x; acc[2][1] += av.z * bv.y; acc[2][2] += av.z * bv.z; acc[2][3] += av.z * bv.w;
            acc[3][0] += av.w * bv.x; acc[3][1] += av.w * bv.y; acc[3][2] += av.w * bv.z; acc[3][3] += av.w * bv.w;
        }
        __syncthreads();
    }
    #pragma unroll
    for (int a = 0; a < 4; ++a) {
        int row = ty * 4 + a;
        float4 o = {acc[a][0], acc[a][1], acc[a][2], acc[a][3]};
        *(float4*)(hpart + ((size_t)ky * B + row) * 512 + cb * 64 + tx * 4) = o;
    }
}

// ---------------- h0c0 reduce: sum partials, add bias, init h/c/xbuf ----------------
__global__ __launch_bounds__(256) void h0c0_reduce(const float* __restrict__ hpart,
                                                   const float* __restrict__ b_hid,
                                                   const float* __restrict__ b_cell,
                                                   const float* __restrict__ emb,
                                                   const int* __restrict__ cap_tok,
                                                   const int* __restrict__ order,
                                                   float* __restrict__ h,
                                                   float* __restrict__ c,
                                                   float* __restrict__ xbuf) {
    int b = blockIdx.x, tid = threadIdx.x;
    float s0 = 0.f, s1 = 0.f;
    #pragma unroll
    for (int ky = 0; ky < 8; ++ky) {
        const float* hp = hpart + ((size_t)ky * B + b) * 512;
        s0 += hp[tid];
        s1 += hp[256 + tid];
    }
    float h0 = s0 + b_hid[tid];
    h[b * D + tid] = h0;
    c[b * D + tid] = s1 + b_cell[tid];
    xbuf[(size_t)b * KX + 2304 + tid] = h0;
    int tok0 = cap_tok[order[b] * L + 0];
    xbuf[(size_t)b * KX + tid] = emb[(size_t)tok0 * EM + tid];
}

// ---------------- fe = feat[order] @ Wf + bf; 64x64 tiles, grid (196,4) ----------------
__global__ __launch_bounds__(256) void fe_gemm(const float* __restrict__ feat,
                                               const int* __restrict__ order,
                                               const float* __restrict__ Wf,
                                               const float* __restrict__ bf,
                                               float* __restrict__ fe) {
    __shared__ float As[32][68];
    __shared__ float Bs[32][64];
    __shared__ int srcRow[64];
    int rowBlock = blockIdx.x;   // 0..195
    int colBlock = blockIdx.y;   // 0..3
    int tid = threadIdx.x;
    if (tid < 64) {
        int gr = rowBlock * 64 + tid;
        int b = gr / P, p = gr % P;
        srcRow[tid] = order[b] * P + p;
    }
    __syncthreads();
    int tx = tid & 15, ty = tid >> 4;
    float acc[4][4] = {};
    for (int k0 = 0; k0 < E; k0 += 32) {
        #pragma unroll
        for (int q = 0; q < 2; ++q) {
            int idx = q * 256 + tid;
            int kv = idx & 7, m = idx >> 3;
            float4 v = *(const float4*)(feat + (size_t)srcRow[m] * E + k0 + kv * 4);
            As[kv * 4 + 0][m] = v.x;
            As[kv * 4 + 1][m] = v.y;
            As[kv * 4 + 2][m] = v.z;
            As[kv * 4 + 3][m] = v.w;
        }
        {
            int n4 = tid & 15, kk = tid >> 4;   // kk 0..15
            float4 v = *(const float4*)(Wf + (size_t)(k0 + kk) * H_ + colBlock * 64 + n4 * 4);
            *(float4*)&Bs[kk][n4 * 4] = v;
            int kk2 = kk + 16;
            float4 v2 = *(const float4*)(Wf + (size_t)(k0 + kk2) * H_ + colBlock * 64 + n4 * 4);
            *(float4*)&Bs[kk2][n4 * 4] = v2;
        }
        __syncthreads();
        #pragma unroll
        for (int kk = 0; kk < 32; ++kk) {
            float4 av = *(const float4*)&As[kk][ty * 4];
            float4 bv = *(const float4*)&Bs[kk][tx * 4];
            acc[0][0] += av.x * bv.x; acc[0][1] += av.x * bv.y; acc[0][2] += av.x * bv.z; acc[0][3] += av.x * bv.w;
            acc[1][0] += av.y * bv.x; acc[1][1] += av.y * bv.y; acc[1][2] += av.y * bv.z; acc[1][3] += av.y * bv.w;
            acc[2][0] += av.z * bv.x; acc[2][1] += av.z * bv.y; acc[2][2] += av.z * bv.z; acc[2][3] += av.z * bv.w;
            acc[3][0] += av.w * bv.x; acc[3][1] += av.w * bv.y; acc[3][2] += av.w * bv.z; acc[3][3] += av.w * bv.w;
        }
        __syncthreads();
    }
    float4 bias = *(const float4*)(bf + colBlock * 64 + tx * 4);
    #pragma unroll
    for (int a = 0; a < 4; ++a) {
        int gr = rowBlock * 64 + ty * 4 + a;
        float4 o;
        o.x = acc[a][0] + bias.x;
        o.y = acc[a][1] + bias.y;
        o.z = acc[a][2] + bias.z;
        o.w = acc[a][3] + bias.w;
        *(float4*)(fe + (size_t)gr * H_ + colBlock * 64 + tx * 4) = o;
    }
}

// ---------------- fused: LSTM pointwise (step t-1) + attention (step t) ----------------
__global__ __launch_bounds__(256) void attn_pw(const int* __restrict__ target,
                                               const float* __restrict__ gpart,
                                               const float* __restrict__ b_ih,
                                               const float* __restrict__ b_hh,
                                               const float* __restrict__ emb,
                                               const int* __restrict__ cap_tok,
                                               const int* __restrict__ order,
                                               const float* __restrict__ Wh,
                                               const float* __restrict__ bh,
                                               const float* __restrict__ We,
                                               const float* __restrict__ be,
                                               const float* __restrict__ fe,
                                               float* __restrict__ h,
                                               float* __restrict__ c,
                                               float* __restrict__ hn_all,
                                               float* __restrict__ xbuf,
                                               float* __restrict__ wbuf,
                                               float* __restrict__ out2,
                                               int t) {
    int b = blockIdx.x;
    int tgt = target[b];
    bool pw_active = (t > 0) && (tgt > t - 1);
    bool at_active = (tgt > t);
    if (!pw_active && !at_active) return;
    __shared__ float hs[D];
    __shared__ float hes[D];
    __shared__ float es[P];
    __shared__ float red[4];
    int tid = threadIdx.x;
    if (pw_active) {
        int d = tid;
        float gi = b_ih[d] + b_hh[d];
        float gf = b_ih[D + d] + b_hh[D + d];
        float gg = b_ih[2 * D + d] + b_hh[2 * D + d];
        float go = b_ih[3 * D + d] + b_hh[3 * D + d];
        #pragma unroll
        for (int ky = 0; ky < 8; ++ky) {
            const float* gp = gpart + ((size_t)ky * B + b) * 1024;
            gi += gp[d];
            gf += gp[D + d];
            gg += gp[2 * D + d];
            go += gp[3 * D + d];
        }
        float c_old = c[b * D + d];
        float si = 1.f / (1.f + expf(-gi));
        float sf = 1.f / (1.f + expf(-gf));
        float so = 1.f / (1.f + expf(-go));
        float cn = sf * c_old + si * tanhf(gg);
        float hnv = so * tanhf(cn);
        c[b * D + d] = cn;
        h[b * D + d] = hnv;
        hs[d] = hnv;
        hn_all[((size_t)(t - 1) * B + b) * D + d] = hnv;
        xbuf[(size_t)b * KX + 2304 + d] = hnv;
        int tokn = cap_tok[order[b] * L + t];
        xbuf[(size_t)b * KX + d] = emb[(size_t)tokn * EM + d];
    } else {
        hs[tid] = h[b * D + tid];
    }
    __syncthreads();
    if (!at_active) return;
    float acc = 0.f;
    #pragma unroll 8
    for (int k = 0; k < D; ++k) acc += hs[k] * Wh[(size_t)k * H_ + tid];
    hes[tid] = acc + bh[tid];
    __syncthreads();
    int wave = tid >> 6, lane = tid & 63;
    float4 he4 = *(const float4*)&hes[lane * 4];
    float4 we4 = *(const float4*)(We + lane * 4);
    for (int p = wave; p < P; p += 4) {
        float4 fv = *(const float4*)(fe + ((size_t)b * P + p) * H_ + lane * 4);
        float x0 = fv.x + he4.x; x0 = x0 > 0.f ? x0 : 0.f;
        float x1 = fv.y + he4.y; x1 = x1 > 0.f ? x1 : 0.f;
        float x2 = fv.z + he4.z; x2 = x2 > 0.f ? x2 : 0.f;
        float x3 = fv.w + he4.w; x3 = x3 > 0.f ? x3 : 0.f;
        float s = x0 * we4.x + x1 * we4.y + x2 * we4.z + x3 * we4.w;
        #pragma unroll
        for (int off = 32; off > 0; off >>= 1) s += __shfl_down(s, off);
        if (lane == 0) es[p] = s + be[0];
    }
    __syncthreads();
    float mx = -1e30f;
    for (int p = tid; p < P; p += 256) mx = fmaxf(mx, es[p]);
    #pragma unroll
    for (int off = 32; off > 0; off >>= 1) mx = fmaxf(mx, __shfl_down(mx, off));
    if (lane == 0) red[wave] = mx;
    __syncthreads();
    mx = fmaxf(fmaxf(red[0], red[1]), fmaxf(red[2], red[3]));
    __syncthreads();
    float sum = 0.f;
    for (int p = tid; p < P; p += 256) {
        float ex = expf(es[p] - mx);
        es[p] = ex;
        sum += ex;
    }
    #pragma unroll
    for (int off = 32; off > 0; off >>= 1) sum += __shfl_down(sum, off);
    if (lane == 0) red[wave] = sum;
    __syncthreads();
    sum = red[0] + red[1] + red[2] + red[3];
    float inv = 1.0f / sum;
    for (int p = tid; p < P; p += 256) {
        float wv = es[p] * inv;
        wbuf[b * P + p] = wv;
        out2[((size_t)b * T + t) * P + p] = wv;
    }
}

// ---------------- ctx+gate -> xbuf[b][256:2304]; grid (B,8) ----------------
__global__ __launch_bounds__(256) void ctx_kernel(const float* __restrict__ feat,
                                                  const int* __restrict__ order,
                                                  const float* __restrict__ wbuf,
                                                  const float* __restrict__ W_gate,
                                                  const float* __restrict__ b_gate,
                                                  const float* __restrict__ h,
                                                  const int* __restrict__ target,
                                                  float* __restrict__ xbuf,
                                                  int t) {
    int b = blockIdx.x;
    if (target[b] <= t) return;
    int y = blockIdx.y;
    __shared__ float ws_[P];
    __shared__ float hs[D];
    __shared__ float4 rc[3][64];
    __shared__ float4 rg[3][64];
    int tid = threadIdx.x;
    if (tid < P) ws_[tid] = wbuf[b * P + tid];
    hs[tid] = h[b * D + tid];
    __syncthreads();
    int c4 = tid & 63, q = tid >> 6;
    int src = order[b];
    const float4* f4 = (const float4*)(feat + (size_t)src * P * E) + y * 64 + c4;
    float4 acc = {0.f, 0.f, 0.f, 0.f};
    for (int p = q * 49; p < q * 49 + 49; ++p) {
        float w = ws_[p];
        float4 fv = f4[(size_t)p * 512];
        acc.x += w * fv.x; acc.y += w * fv.y; acc.z += w * fv.z; acc.w += w * fv.w;
    }
    const float4* g4 = (const float4*)W_gate + y * 64 + c4;
    float4 gacc = {0.f, 0.f, 0.f, 0.f};
    for (int k = q * 64; k < q * 64 + 64; ++k) {
        float hv = hs[k];
        float4 wv = g4[(size_t)k * 512];
        gacc.x += hv * wv.x; gacc.y += hv * wv.y; gacc.z += hv * wv.z; gacc.w += hv * wv.w;
    }
    if (q) { rc[q - 1][c4] = acc; rg[q - 1][c4] = gacc; }
    __syncthreads();
    if (q == 0) {
        #pragma unroll
        for (int j = 0; j < 3; ++j) {
            float4 a = rc[j][c4], g = rg[j][c4];
            acc.x += a.x; acc.y += a.y; acc.z += a.z; acc.w += a.w;
            gacc.x += g.x; gacc.y += g.y; gacc.z += g.z; gacc.w += g.w;
        }
        float4 gb = *(const float4*)(b_gate + (y * 64 + c4) * 4);
        float4 o;
        o.x = acc.x / (1.f + expf(-(gacc.x + gb.x)));
        o.y = acc.y / (1.f + expf(-(gacc.y + gb.y)));
        o.z = acc.z / (1.f + expf(-(gacc.z + gb.z)));
        o.w = acc.w / (1.f + expf(-(gacc.w + gb.w)));
        *(float4*)(xbuf + (size_t)b * KX + EM + (y * 64 + c4) * 4) = o;
    }
}

// ---------------- gate GEMM: K split 8-way ----------------
__global__ __launch_bounds__(256) void lstm_gemm(const float* __restrict__ xbuf,
                                                 const float* __restrict__ W_ih,
                                                 const float* __restrict__ W_hh,
                                                 float* __restrict__ gpart) {
    __shared__ float As[32][68];
    __shared__ float Bs[32][64];
    int cb = blockIdx.x;   // 0..15
    int ky = blockIdx.y;   // 0..7
    int tid = threadIdx.x;
    int tx = tid & 15, ty = tid >> 4;
    float acc[4][4] = {};
    int k0base = ky * 320;
    for (int k0 = k0base; k0 < k0base + 320; k0 += 32) {
        #pragma unroll
        for (int q = 0; q < 2; ++q) {
            int idx = q * 256 + tid;
            int kv = idx & 7, m = idx >> 3;
            float4 v = *(const float4*)(xbuf + (size_t)m * KX + k0 + kv * 4);
            As[kv * 4 + 0][m] = v.x;
            As[kv * 4 + 1][m] = v.y;
            As[kv * 4 + 2][m] = v.z;
            As[kv * 4 + 3][m] = v.w;
        }
        #pragma unroll
        for (int q = 0; q < 2; ++q) {
            int idx = q * 256 + tid;
            int n4 = idx & 15, kk = idx >> 4;
            int k = k0 + kk;
            const float* src = (k < EM + E) ? (W_ih + (size_t)k * 1024)
                                            : (W_hh + (size_t)(k - EM - E) * 1024);
            float4 v = *(const float4*)(src + cb * 64 + n4 * 4);
            *(float4*)&Bs[kk][n4 * 4] = v;
        }
        __syncthreads();
        #pragma unroll
        for (int kk = 0; kk < 32; ++kk) {
            float4 av = *(const float4*)&As[kk][ty * 4];
            float4 bv = *(const float4*)&Bs[kk][tx * 4];
            acc[0][0] += av.x * bv.x; acc[0][1] += av.x * bv.y; acc[0][2] += av.x * bv.z; acc[0][3] += av.x * bv.w;
            acc[1][0] += av.y * bv.x; acc[1][1] += av.y * bv.y; acc[1][2] += av.y * bv.z; acc[1][3] += av.y * bv.w;
            acc[2][0] += av.z * bv.x; acc[2][1] += av.z * bv.y; acc[2][2] += av.z * bv.z; acc[2][3] += av.z * bv.w;
            acc[3][0] += av.w * bv.x; acc[3][1] += av.w * bv.y; acc[3][2] += av.w * bv.z; acc[3][3] += av.w * bv.w;
        }
        __syncthreads();
    }
    #pragma unroll
    for (int a = 0; a < 4; ++a) {
        int bidx = ty * 4 + a;
        float4 o = {acc[a][0], acc[a][1], acc[a][2], acc[a][3]};
        *(float4*)(gpart + ((size_t)ky * B + bidx) * 1024 + cb * 64 + tx * 4) = o;
    }
}

// ================= persistent cooperative loop: all T steps in one dispatch =================
// Grid: 512 blocks x 256 threads (2 blocks/CU guaranteed by __launch_bounds__(256,2), 17KB LDS).
// Phase A (blocks 0..63):  LSTM pointwise(t-1) + he matvec + attn scores + softmax  [== attn_pw]
// Phase B (all 512):       ctx + gate -> xbuf                                        [== ctx_kernel]
// Phase C (blocks 0..127): gate GEMM split-K 8                                       [== lstm_gemm]
// Dependencies w->ctx, xbuf->gemm, gpart->pw each separated by grid.sync().
__global__ __launch_bounds__(256, 2) void loop_kernel(
        const int* __restrict__ target,
        float* __restrict__ gpart,
        const float* __restrict__ b_ih,
        const float* __restrict__ b_hh,
        const float* __restrict__ emb,
        const int* __restrict__ cap_tok,
        const int* __restrict__ order,
        const float* __restrict__ Wh,
        const float* __restrict__ bh,
        const float* __restrict__ We,
        const float* __restrict__ be,
        const float* __restrict__ fe,
        float* __restrict__ h,
        float* __restrict__ c,
        float* __restrict__ hn_all,
        float* __restrict__ xbuf,
        float* __restrict__ wbuf,
        float* __restrict__ out2,
        const float* __restrict__ feat,
        const float* __restrict__ W_gate,
        const float* __restrict__ b_gate,
        const float* __restrict__ W_ih,
        const float* __restrict__ W_hh) {
    cg::grid_group grid = cg::this_grid();
    __shared__ __align__(16) char smem_raw[17408];
    int bid = blockIdx.x;
    int tid = threadIdx.x;

    for (int t = 0; ; ++t) {
        // -------- Phase A --------
        if (bid < B) {
            float* hs  = (float*)smem_raw;          // 256
            float* hes = hs + 256;                  // 256
            float* es  = hes + 256;                 // 196 (pad to 200)
            float* red = es + 200;                  // 4
            int b = bid;
            int tgt = target[b];
            bool pw_active = (t > 0) && (tgt > t - 1);
            bool at_active = (t < T) && (tgt > t);
            if (pw_active || at_active) {
                if (pw_active) {
                    int d = tid;
                    float gi = b_ih[d] + b_hh[d];
                    float gf = b_ih[D + d] + b_hh[D + d];
                    float gg = b_ih[2 * D + d] + b_hh[2 * D + d];
                    float go = b_ih[3 * D + d] + b_hh[3 * D + d];
                    #pragma unroll
                    for (int ky = 0; ky < 8; ++ky) {
                        const float* gp = gpart + ((size_t)ky * B + b) * 1024;
                        gi += gp[d];
                        gf += gp[D + d];
                        gg += gp[2 * D + d];
                        go += gp[3 * D + d];
                    }
                    float c_old = c[b * D + d];
                    float si = 1.f / (1.f + expf(-gi));
                    float sf = 1.f / (1.f + expf(-gf));
                    float so = 1.f / (1.f + expf(-go));
                    float cn = sf * c_old + si * tanhf(gg);
                    float hnv = so * tanhf(cn);
                    c[b * D + d] = cn;
                    h[b * D + d] = hnv;
                    hs[d] = hnv;
                    hn_all[((size_t)(t - 1) * B + b) * D + d] = hnv;
                    xbuf[(size_t)b * KX + 2304 + d] = hnv;
                    int tokn = cap_tok[order[b] * L + t];
                    xbuf[(size_t)b * KX + d] = emb[(size_t)tokn * EM + d];
                } else {
                    hs[tid] = h[b * D + tid];
                }
                __syncthreads();
                if (at_active) {
                    float acc = 0.f;
                    #pragma unroll 8
                    for (int k = 0; k < D; ++k) acc += hs[k] * Wh[(size_t)k * H_ + tid];
                    hes[tid] = acc + bh[tid];
                    __syncthreads();
                    int wave = tid >> 6, lane = tid & 63;
                    float4 he4 = *(const float4*)&hes[lane * 4];
                    float4 we4 = *(const float4*)(We + lane * 4);
                    for (int p = wave; p < P; p += 4) {
                        float4 fv = *(const float4*)(fe + ((size_t)b * P + p) * H_ + lane * 4);
                        float x0 = fv.x + he4.x; x0 = x0 > 0.f ? x0 : 0.f;
                        float x1 = fv.y + he4.y; x1 = x1 > 0.f ? x1 : 0.f;
                        float x2 = fv.z + he4.z; x2 = x2 > 0.f ? x2 : 0.f;
                        float x3 = fv.w + he4.w; x3 = x3 > 0.f ? x3 : 0.f;
                        float s = x0 * we4.x + x1 * we4.y + x2 * we4.z + x3 * we4.w;
                        #pragma unroll
                        for (int off = 32; off > 0; off >>= 1) s += __shfl_down(s, off);
                        if (lane == 0) es[p] = s + be[0];
                    }
                    __syncthreads();
                    float mx = -1e30f;
                    for (int p = tid; p < P; p += 256) mx = fmaxf(mx, es[p]);
                    #pragma unroll
                    for (int off = 32; off > 0; off >>= 1) mx = fmaxf(mx, __shfl_down(mx, off));
                    if (lane == 0) red[wave] = mx;
                    __syncthreads();
                    mx = fmaxf(fmaxf(red[0], red[1]), fmaxf(red[2], red[3]));
                    __syncthreads();
                    float sum = 0.f;
                    for (int p = tid; p < P; p += 256) {
                        float ex = expf(es[p] - mx);
                        es[p] = ex;
                        sum += ex;
                    }
                    #pragma unroll
                    for (int off = 32; off > 0; off >>= 1) sum += __shfl_down(sum, off);
                    if (lane == 0) red[wave] = sum;
                    __syncthreads();
                    sum = red[0] + red[1] + red[2] + red[3];
                    float inv = 1.0f / sum;
                    for (int p = tid; p < P; p += 256) {
                        float wv = es[p] * inv;
                        wbuf[b * P + p] = wv;
                        out2[((size_t)b * T + t) * P + p] = wv;
                    }
                }
            }
        }
        if (t == T) break;     // uniform across all blocks: equal sync counts
        grid.sync();           // w, h(t) ready for ctx

        // -------- Phase B --------
        {
            int b = bid >> 3, y = bid & 7;
            if (target[b] > t) {
                float*  ws_ = (float*)smem_raw;                  // 196 (pad 200)
                float*  hsB = ws_ + 200;                         // 256
                float4* rc  = (float4*)(smem_raw + 1824);        // 3*64
                float4* rg  = rc + 192;                          // 3*64
                if (tid < P) ws_[tid] = wbuf[b * P + tid];
                hsB[tid] = h[b * D + tid];
                __syncthreads();
                int c4 = tid & 63, q = tid >> 6;
                int src = order[b];
                const float4* f4 = (const float4*)(feat + (size_t)src * P * E) + y * 64 + c4;
                float4 acc = {0.f, 0.f, 0.f, 0.f};
                for (int p = q * 49; p < q * 49 + 49; ++p) {
                    float w = ws_[p];
                    float4 fv = f4[(size_t)p * 512];
                    acc.x += w * fv.x; acc.y += w * fv.y; acc.z += w * fv.z; acc.w += w * fv.w;
                }
                const float4* g4 = (const float4*)W_gate + y * 64 + c4;
                float4 gacc = {0.f, 0.f, 0.f, 0.f};
                for (int k = q * 64; k < q * 64 + 64; ++k) {
                    float hv = hsB[k];
                    float4 wv = g4[(size_t)k * 512];
                    gacc.x += hv * wv.x; gacc.y += hv * wv.y; gacc.z += hv * wv.z; gacc.w += hv * wv.w;
                }
                if (q) { rc[(q - 1) * 64 + c4] = acc; rg[(q - 1) * 64 + c4] = gacc; }
                __syncthreads();
                if (q == 0) {
                    #pragma unroll
                    for (int j = 0; j < 3; ++j) {
                        float4 a = rc[j * 64 + c4], g = rg[j * 64 + c4];
                        acc.x += a.x; acc.y += a.y; acc.z += a.z; acc.w += a.w;
                        gacc.x += g.x; gacc.y += g.y; gacc.z += g.z; gacc.w += g.w;
                    }
                    float4 gb = *(const float4*)(b_gate + (y * 64 + c4) * 4);
                    float4 o;
                    o.x = acc.x / (1.f + expf(-(gacc.x + gb.x)));
                    o.y = acc.y / (1.f + expf(-(gacc.y + gb.y)));
                    o.z = acc.z / (1.f + expf(-(gacc.z + gb.z)));
                    o.w = acc.w / (1.f + expf(-(gacc.w + gb.w)));
                    *(float4*)(xbuf + (size_t)b * KX + EM + (y * 64 + c4) * 4) = o;
                }
            }
        }
        grid.sync();           // xbuf ready for gate GEMM

        // -------- Phase C --------
        if (bid < 128) {
            float (*As)[68] = (float (*)[68])smem_raw;                 // 32x68
            float (*Bs)[64] = (float (*)[64])(smem_raw + 8704);        // 32x64
            int cb = bid & 15, ky = bid >> 4;
            int tx = tid & 15, ty = tid >> 4;
            float acc[4][4] = {};
            int k0base = ky * 320;
            for (int k0 = k0base; k0 < k0base + 320; k0 += 32) {
                #pragma unroll
                for (int q = 0; q < 2; ++q) {
                    int idx = q * 256 + tid;
                    int kv = idx & 7, m = idx >> 3;
                    float4 v = *(const float4*)(xbuf + (size_t)m * KX + k0 + kv * 4);
                    As[kv * 4 + 0][m] = v.x;
                    As[kv * 4 + 1][m] = v.y;
                    As[kv * 4 + 2][m] = v.z;
                    As[kv * 4 + 3][m] = v.w;
                }
                #pragma unroll
                for (int q = 0; q < 2; ++q) {
                    int idx = q * 256 + tid;
                    int n4 = idx & 15, kk = idx >> 4;
                    int k = k0 + kk;
                    const float* src = (k < EM + E) ? (W_ih + (size_t)k * 1024)
                                                    : (W_hh + (size_t)(k - EM - E) * 1024);
                    float4 v = *(const float4*)(src + cb * 64 + n4 * 4);
                    *(float4*)&Bs[kk][n4 * 4] = v;
                }
                __syncthreads();
                #pragma unroll
                for (int kk = 0; kk < 32; ++kk) {
                    float4 av = *(const float4*)&As[kk][ty * 4];
                    float4 bv = *(const float4*)&Bs[kk][tx * 4];
                    acc[0][0] += av.x * bv.x; acc[0][1] += av.x * bv.y; acc[0][2] += av.x * bv.z; acc[0][3] += av.x * bv.w;
                    acc[1][0] += av.y * bv.x; acc[1][1] += av.y * bv.y; acc[1][2] += av.y * bv.z; acc[1][3] += av.y * bv.w;
                    acc[2][0] += av.z * bv.x; acc[2][1] += av.z * bv.y; acc[2][2] += av.z * bv.z; acc[2][3] += av.z * bv.w;
                    acc[3][0] += av.w * bv.x; acc[3][1] += av.w * bv.y; acc[3][2] += av.w * bv.z; acc[3][3] += av.w * bv.w;
                }
                __syncthreads();
            }
            #pragma unroll
            for (int a = 0; a < 4; ++a) {
                int bidx = ty * 4 + a;
                float4 o = {acc[a][0], acc[a][1], acc[a][2], acc[a][3]};
                *(float4*)(gpart + ((size_t)ky * B + bidx) * 1024 + cb * 64 + tx * 4) = o;
            }
        }
        grid.sync();           // gpart ready for next-step pointwise
    }
}

// ---------------- batched head over all t: grid (157, 62) ----------------
__global__ __launch_bounds__(256) void head_batch(const float* __restrict__ hn_all,
                                                  const float* __restrict__ W_head,
                                                  const float* __restrict__ b_head,
                                                  const int* __restrict__ target,
                                                  float* __restrict__ out1) {
    int by = blockIdx.y;
    int t = by >> 1, qh = by & 1;
    if (target[qh * 32] <= t) return;   // sorted: whole 32-row tile inactive
    __shared__ float hs[32][260];
    int cb = blockIdx.x;
    int tid = threadIdx.x;
    #pragma unroll
    for (int q = 0; q < 8; ++q) {
        int idx = q * 256 + tid;
        int r = idx >> 6, kq = idx & 63;
        float4 v = *(const float4*)(hn_all + ((size_t)t * B + qh * 32 + r) * D + kq * 4);
        *(float4*)&hs[r][kq * 4] = v;
    }
    __syncthreads();
    int col = cb * 64 + (tid & 63);
    int rgrp = (tid >> 6) * 8;
    if (col < V) {
        float acc[8] = {};
        for (int kq = 0; kq < 64; ++kq) {
            float w0 = W_head[(size_t)(kq * 4 + 0) * V + col];
            float w1 = W_head[(size_t)(kq * 4 + 1) * V + col];
            float w2 = W_head[(size_t)(kq * 4 + 2) * V + col];
            float w3 = W_head[(size_t)(kq * 4 + 3) * V + col];
            #pragma unroll
            for (int r = 0; r < 8; ++r) {
                float4 hv = *(const float4*)&hs[rgrp + r][kq * 4];
                acc[r] += hv.x * w0 + hv.y * w1 + hv.z * w2 + hv.w * w3;
            }
        }
        float bh_ = b_head[col];
        #pragma unroll
        for (int r = 0; r < 8; ++r) {
            int brow = qh * 32 + rgrp + r;
            if (target[brow] > t)
                out1[((size_t)brow * T + t) * V + col] = acc[r] + bh_;
        }
    }
}

extern "C" void kernel_launch(void* const* d_in, const int* in_sizes, int n_in,
                              void* d_out, int out_size, void* d_ws, size_t ws_size,
                              hipStream_t stream) {
    const float* feat   = (const float*)d_in[0];
    const int*   tok    = (const int*)d_in[1];
    const int*   clen   = (const int*)d_in[2];
    const float* Wf     = (const float*)d_in[3];
    const float* bf     = (const float*)d_in[4];
    const float* Wh     = (const float*)d_in[5];
    const float* bh     = (const float*)d_in[6];
    const float* We     = (const float*)d_in[7];
    const float* be     = (const float*)d_in[8];
    const float* emb    = (const float*)d_in[9];
    const float* W_ih   = (const float*)d_in[10];
    const float* b_ih   = (const float*)d_in[11];
    const float* W_hh   = (const float*)d_in[12];
    const float* b_hh   = (const float*)d_in[13];
    const float* W_hid  = (const float*)d_in[14];
    const float* b_hid  = (const float*)d_in[15];
    const float* W_cell = (const float*)d_in[16];
    const float* b_cell = (const float*)d_in[17];
    const float* W_gate = (const float*)d_in[18];
    const float* b_gate = (const float*)d_in[19];
    const float* W_head = (const float*)d_in[20];
    const float* b_head = (const float*)d_in[21];

    float* out1 = (float*)d_out;
    float* out2 = out1 + (size_t)B * T * V;

    char* wp = (char*)d_ws;
    int* order   = (int*)wp;           wp += 256;
    int* targetp = (int*)wp;           wp += 256;
    float* fe    = (float*)wp;         wp += (size_t)B * P * H_ * sizeof(float);
    float* hbuf  = (float*)wp;         wp += (size_t)B * D * sizeof(float);
    float* cbuf  = (float*)wp;         wp += (size_t)B * D * sizeof(float);
    float* wbuf  = (float*)wp;         wp += (size_t)B * P * sizeof(float);
    float* xbuf  = (float*)wp;         wp += (size_t)B * KX * sizeof(float);
    float* gpart = (float*)wp;         wp += (size_t)8 * B * 1024 * sizeof(float);
    float* mean_feat = (float*)wp;     wp += (size_t)B * E * sizeof(float);
    float* hpart = (float*)wp;         wp += (size_t)8 * B * 512 * sizeof(float);
    float* hn_all = (float*)wp;        wp += (size_t)T * B * D * sizeof(float);

    hipMemsetAsync(d_out, 0, (size_t)out_size * sizeof(float), stream);

    sort_kernel<<<1, 64, 0, stream>>>(clen, order, targetp);
    mean_kernel<<<dim3(B, E / 256), 256, 0, stream>>>(feat, order, mean_feat);
    h0c0_gemm<<<dim3(8, 8), 256, 0, stream>>>(mean_feat, W_hid, W_cell, hpart);
    h0c0_reduce<<<B, 256, 0, stream>>>(hpart, b_hid, b_cell, emb, tok, order,
                                       hbuf, cbuf, xbuf);
    fe_gemm<<<dim3(196, 4), 256, 0, stream>>>(feat, order, Wf, bf, fe);

    // ---- persistent cooperative loop (all T steps, 3 grid syncs/step) ----
    void* kargs[] = {
        (void*)&targetp, (void*)&gpart, (void*)&b_ih, (void*)&b_hh,
        (void*)&emb, (void*)&tok, (void*)&order, (void*)&Wh, (void*)&bh,
        (void*)&We, (void*)&be, (void*)&fe, (void*)&hbuf, (void*)&cbuf,
        (void*)&hn_all, (void*)&xbuf, (void*)&wbuf, (void*)&out2,
        (void*)&feat, (void*)&W_gate, (void*)&b_gate, (void*)&W_ih, (void*)&W_hh
    };
    hipError_t cerr = hipLaunchCooperativeKernel((const void*)loop_kernel,
                                                 dim3(512), dim3(256),
                                                 kargs, 0, stream);
    if (cerr != hipSuccess) {
        // Fallback: original 3-kernel-per-step loop
        for (int t = 0; t < T; ++t) {
            attn_pw<<<B, 256, 0, stream>>>(targetp, gpart, b_ih, b_hh, emb, tok, order,
                                           Wh, bh, We, be, fe, hbuf, cbuf, hn_all,
                                           xbuf, wbuf, out2, t);
            ctx_kernel<<<dim3(B, 8), 256, 0, stream>>>(feat, order, wbuf, W_gate, b_gate,
                                                       hbuf, targetp, xbuf, t);
            lstm_gemm<<<dim3(16, 8), 256, 0, stream>>>(xbuf, W_ih, W_hh, gpart);
        }
        attn_pw<<<B, 256, 0, stream>>>(targetp, gpart, b_ih, b_hh, emb, tok, order,
                                       Wh, bh, We, be, fe, hbuf, cbuf, hn_all,
                                       xbuf, wbuf, out2, T);
    }

    head_batch<<<dim3(157, 62), 256, 0, stream>>>(hn_all, W_head, b_head, targetp, out1);
}

// Round 2
// 2732.180 us; speedup vs baseline: 3.8840x; 3.8840x over previous
//
#include <hip/hip_runtime.h>
#include <math.h>

#define B 64
#define P 196
#define E 2048
#define D 256
#define H_ 256
#define EM 256
#define V 10000
#define L 32
#define T 31
#define KX 2560   // EM + E + D

// ---------------- sort: stable argsort descending by length ----------------
__global__ __launch_bounds__(64) void sort_kernel(const int* __restrict__ clen,
                                                  int* __restrict__ order,
                                                  int* __restrict__ target) {
    __shared__ int len_s[B];
    int i = threadIdx.x;
    len_s[i] = clen[i];
    __syncthreads();
    int li = len_s[i];
    int rank = 0;
    for (int j = 0; j < B; ++j) {
        int lj = len_s[j];
        if (lj > li || (lj == li && j < i)) rank++;
    }
    order[rank] = i;
    target[rank] = li - 1;
}

// ---------------- mean_feat[b][e] = mean_p feat[src][p][e] ----------------
__global__ __launch_bounds__(256) void mean_kernel(const float* __restrict__ feat,
                                                   const int* __restrict__ order,
                                                   float* __restrict__ mean_feat) {
    int b = blockIdx.x;
    int e = blockIdx.y * 256 + threadIdx.x;
    int src = order[b];
    const float* fp = feat + (size_t)src * P * E + e;
    float acc = 0.f;
    #pragma unroll 4
    for (int p = 0; p < P; ++p) acc += fp[(size_t)p * E];
    mean_feat[b * E + e] = acc * (1.0f / (float)P);
}

// ---------------- h0c0 as split-K GEMM: hpart[ky][64][512] ----------------
__global__ __launch_bounds__(256) void h0c0_gemm(const float* __restrict__ mean_feat,
                                                 const float* __restrict__ W_hid,
                                                 const float* __restrict__ W_cell,
                                                 float* __restrict__ hpart) {
    __shared__ float As[32][68];
    __shared__ float Bs[32][64];
    int cb = blockIdx.x;   // 0..7
    int ky = blockIdx.y;   // 0..7
    int tid = threadIdx.x;
    int tx = tid & 15, ty = tid >> 4;
    const float* Wsrc;
    int ncol0;
    if (cb < 4) { Wsrc = W_hid;  ncol0 = cb * 64; }
    else        { Wsrc = W_cell; ncol0 = (cb - 4) * 64; }
    float acc[4][4] = {};
    for (int k0 = ky * 256; k0 < ky * 256 + 256; k0 += 32) {
        #pragma unroll
        for (int q = 0; q < 2; ++q) {
            int idx = q * 256 + tid;
            int kv = idx & 7, m = idx >> 3;
            float4 v = *(const float4*)(mean_feat + (size_t)m * E + k0 + kv * 4);
            As[kv * 4 + 0][m] = v.x;
            As[kv * 4 + 1][m] = v.y;
            As[kv * 4 + 2][m] = v.z;
            As[kv * 4 + 3][m] = v.w;
        }
        #pragma unroll
        for (int q = 0; q < 2; ++q) {
            int idx = q * 256 + tid;
            int n4 = idx & 15, kk = idx >> 4;
            float4 v = *(const float4*)(Wsrc + (size_t)(k0 + kk) * 256 + ncol0 + n4 * 4);
            *(float4*)&Bs[kk][n4 * 4] = v;
        }
        __syncthreads();
        #pragma unroll
        for (int kk = 0; kk < 32; ++kk) {
            float4 av = *(const float4*)&As[kk][ty * 4];
            float4 bv = *(const float4*)&Bs[kk][tx * 4];
            acc[0][0] += av.x * bv.x; acc[0][1] += av.x * bv.y; acc[0][2] += av.x * bv.z; acc[0][3] += av.x * bv.w;
            acc[1][0] += av.y * bv.x; acc[1][1] += av.y * bv.y; acc[1][2] += av.y * bv.z; acc[1][3] += av.y * bv.w;
            acc[2][0] += av.z * bv.x; acc[2][1] += av.z * bv.y; acc[2][2] += av.z * bv.z; acc[2][3] += av.z * bv.w;
            acc[3][0] += av.w * bv.x; acc[3][1] += av.w * bv.y; acc[3][2] += av.w * bv.z; acc[3][3] += av.w * bv.w;
        }
        __syncthreads();
    }
    #pragma unroll
    for (int a = 0; a < 4; ++a) {
        int row = ty * 4 + a;
        float4 o = {acc[a][0], acc[a][1], acc[a][2], acc[a][3]};
        *(float4*)(hpart + ((size_t)ky * B + row) * 512 + cb * 64 + tx * 4) = o;
    }
}

// ---------------- h0c0 reduce: sum partials, add bias, init h/c/xbuf ----------------
__global__ __launch_bounds__(256) void h0c0_reduce(const float* __restrict__ hpart,
                                                   const float* __restrict__ b_hid,
                                                   const float* __restrict__ b_cell,
                                                   const float* __restrict__ emb,
                                                   const int* __restrict__ cap_tok,
                                                   const int* __restrict__ order,
                                                   float* __restrict__ h,
                                                   float* __restrict__ c0,
                                                   float* __restrict__ xbuf) {
    int b = blockIdx.x, tid = threadIdx.x;
    float s0 = 0.f, s1 = 0.f;
    #pragma unroll
    for (int ky = 0; ky < 8; ++ky) {
        const float* hp = hpart + ((size_t)ky * B + b) * 512;
        s0 += hp[tid];
        s1 += hp[256 + tid];
    }
    float h0 = s0 + b_hid[tid];
    h[b * D + tid] = h0;
    c0[b * D + tid] = s1 + b_cell[tid];
    xbuf[(size_t)b * KX + 2304 + tid] = h0;
    int tok0 = cap_tok[order[b] * L + 0];
    xbuf[(size_t)b * KX + tid] = emb[(size_t)tok0 * EM + tid];
}

// ---------------- fe = feat[order] @ Wf + bf; 64x64 tiles, grid (196,4) ----------------
__global__ __launch_bounds__(256) void fe_gemm(const float* __restrict__ feat,
                                               const int* __restrict__ order,
                                               const float* __restrict__ Wf,
                                               const float* __restrict__ bf,
                                               float* __restrict__ fe) {
    __shared__ float As[32][68];
    __shared__ float Bs[32][64];
    __shared__ int srcRow[64];
    int rowBlock = blockIdx.x;   // 0..195
    int colBlock = blockIdx.y;   // 0..3
    int tid = threadIdx.x;
    if (tid < 64) {
        int gr = rowBlock * 64 + tid;
        int b = gr / P, p = gr % P;
        srcRow[tid] = order[b] * P + p;
    }
    __syncthreads();
    int tx = tid & 15, ty = tid >> 4;
    float acc[4][4] = {};
    for (int k0 = 0; k0 < E; k0 += 32) {
        #pragma unroll
        for (int q = 0; q < 2; ++q) {
            int idx = q * 256 + tid;
            int kv = idx & 7, m = idx >> 3;
            float4 v = *(const float4*)(feat + (size_t)srcRow[m] * E + k0 + kv * 4);
            As[kv * 4 + 0][m] = v.x;
            As[kv * 4 + 1][m] = v.y;
            As[kv * 4 + 2][m] = v.z;
            As[kv * 4 + 3][m] = v.w;
        }
        {
            int n4 = tid & 15, kk = tid >> 4;   // kk 0..15
            float4 v = *(const float4*)(Wf + (size_t)(k0 + kk) * H_ + colBlock * 64 + n4 * 4);
            *(float4*)&Bs[kk][n4 * 4] = v;
            int kk2 = kk + 16;
            float4 v2 = *(const float4*)(Wf + (size_t)(k0 + kk2) * H_ + colBlock * 64 + n4 * 4);
            *(float4*)&Bs[kk2][n4 * 4] = v2;
        }
        __syncthreads();
        #pragma unroll
        for (int kk = 0; kk < 32; ++kk) {
            float4 av = *(const float4*)&As[kk][ty * 4];
            float4 bv = *(const float4*)&Bs[kk][tx * 4];
            acc[0][0] += av.x * bv.x; acc[0][1] += av.x * bv.y; acc[0][2] += av.x * bv.z; acc[0][3] += av.x * bv.w;
            acc[1][0] += av.y * bv.x; acc[1][1] += av.y * bv.y; acc[1][2] += av.y * bv.z; acc[1][3] += av.y * bv.w;
            acc[2][0] += av.z * bv.x; acc[2][1] += av.z * bv.y; acc[2][2] += av.z * bv.z; acc[2][3] += av.z * bv.w;
            acc[3][0] += av.w * bv.x; acc[3][1] += av.w * bv.y; acc[3][2] += av.w * bv.z; acc[3][3] += av.w * bv.w;
        }
        __syncthreads();
    }
    float4 bias = *(const float4*)(bf + colBlock * 64 + tx * 4);
    #pragma unroll
    for (int a = 0; a < 4; ++a) {
        int gr = rowBlock * 64 + ty * 4 + a;
        float4 o;
        o.x = acc[a][0] + bias.x;
        o.y = acc[a][1] + bias.y;
        o.z = acc[a][2] + bias.z;
        o.w = acc[a][3] + bias.w;
        *(float4*)(fe + (size_t)gr * H_ + colBlock * 64 + tx * 4) = o;
    }
}

// ============ fused per-step kernel: pointwise + attention + ctx, grid (B,8) ============
// Each of the 8 y-blocks per batch redundantly computes pointwise LSTM + softmax (cheap,
// keeps everything per-batch => no cross-block dependency), then its 256-col ctx slice.
// c state double-buffered (c_rd/c_wr) so the 8 duplicate blocks never RMW-race.
// Global side-effect writes (c, hn_all, xbuf emb/h, out2) guarded to y==0.
__global__ __launch_bounds__(256) void attn_ctx(const int* __restrict__ target,
                                                const float* __restrict__ gpart,
                                                const float* __restrict__ b_ih,
                                                const float* __restrict__ b_hh,
                                                const float* __restrict__ emb,
                                                const int* __restrict__ cap_tok,
                                                const int* __restrict__ order,
                                                const float* __restrict__ Wh,
                                                const float* __restrict__ bh,
                                                const float* __restrict__ We,
                                                const float* __restrict__ be,
                                                const float* __restrict__ fe,
                                                const float* __restrict__ h0,
                                                const float* __restrict__ c_rd,
                                                float* __restrict__ c_wr,
                                                float* __restrict__ hn_all,
                                                float* __restrict__ xbuf,
                                                float* __restrict__ out2,
                                                const float* __restrict__ feat,
                                                const float* __restrict__ W_gate,
                                                const float* __restrict__ b_gate,
                                                int t) {
    int b = blockIdx.x, y = blockIdx.y, tid = threadIdx.x;
    int tgt = target[b];
    bool pw_active = (t > 0) && (tgt > t - 1);
    bool at_active = (tgt > t);
    if (!at_active && !(pw_active && y == 0)) return;

    __shared__ float hs[D];
    __shared__ float hes[D];
    __shared__ float es[200];
    __shared__ float red[4];
    __shared__ float4 rc[3][64];
    __shared__ float4 rg[3][64];

    // ---- pointwise LSTM (finishes step t-1); all active y-blocks compute hs ----
    if (pw_active) {
        int d = tid;
        float gi = b_ih[d] + b_hh[d];
        float gf = b_ih[D + d] + b_hh[D + d];
        float gg = b_ih[2 * D + d] + b_hh[2 * D + d];
        float go = b_ih[3 * D + d] + b_hh[3 * D + d];
        #pragma unroll
        for (int ky = 0; ky < 8; ++ky) {
            const float* gp = gpart + ((size_t)ky * B + b) * 1024;
            gi += gp[d];
            gf += gp[D + d];
            gg += gp[2 * D + d];
            go += gp[3 * D + d];
        }
        float c_old = c_rd[b * D + d];
        float si = 1.f / (1.f + expf(-gi));
        float sf = 1.f / (1.f + expf(-gf));
        float so = 1.f / (1.f + expf(-go));
        float cn = sf * c_old + si * tanhf(gg);
        float hnv = so * tanhf(cn);
        hs[d] = hnv;
        if (y == 0) {
            c_wr[b * D + d] = cn;
            hn_all[((size_t)(t - 1) * B + b) * D + d] = hnv;
            xbuf[(size_t)b * KX + 2304 + d] = hnv;
            int tokn = cap_tok[order[b] * L + t];
            xbuf[(size_t)b * KX + d] = emb[(size_t)tokn * EM + d];
        }
    } else {
        hs[tid] = h0[b * D + tid];   // only reachable at t == 0
    }
    __syncthreads();
    if (!at_active) return;   // y==0, pointwise-only tail for this batch

    // ---- he = hs @ Wh + bh ----
    {
        float acc = 0.f;
        #pragma unroll 8
        for (int k = 0; k < D; ++k) acc += hs[k] * Wh[(size_t)k * H_ + tid];
        hes[tid] = acc + bh[tid];
    }
    __syncthreads();

    // ---- scores: es[p] = We . relu(fe[b,p] + he) + be ----
    int wave = tid >> 6, lane = tid & 63;
    {
        float4 he4 = *(const float4*)&hes[lane * 4];
        float4 we4 = *(const float4*)(We + lane * 4);
        for (int p = wave; p < P; p += 4) {
            float4 fv = *(const float4*)(fe + ((size_t)b * P + p) * H_ + lane * 4);
            float x0 = fv.x + he4.x; x0 = x0 > 0.f ? x0 : 0.f;
            float x1 = fv.y + he4.y; x1 = x1 > 0.f ? x1 : 0.f;
            float x2 = fv.z + he4.z; x2 = x2 > 0.f ? x2 : 0.f;
            float x3 = fv.w + he4.w; x3 = x3 > 0.f ? x3 : 0.f;
            float s = x0 * we4.x + x1 * we4.y + x2 * we4.z + x3 * we4.w;
            #pragma unroll
            for (int off = 32; off > 0; off >>= 1) s += __shfl_down(s, off);
            if (lane == 0) es[p] = s + be[0];
        }
    }
    __syncthreads();

    // ---- softmax over es[0..195] -> normalized w stored back into es ----
    {
        float mx = -1e30f;
        for (int p = tid; p < P; p += 256) mx = fmaxf(mx, es[p]);
        #pragma unroll
        for (int off = 32; off > 0; off >>= 1) mx = fmaxf(mx, __shfl_down(mx, off));
        if (lane == 0) red[wave] = mx;
        __syncthreads();
        mx = fmaxf(fmaxf(red[0], red[1]), fmaxf(red[2], red[3]));
        __syncthreads();
        float sum = 0.f;
        for (int p = tid; p < P; p += 256) {
            float ex = expf(es[p] - mx);
            es[p] = ex;
            sum += ex;
        }
        #pragma unroll
        for (int off = 32; off > 0; off >>= 1) sum += __shfl_down(sum, off);
        if (lane == 0) red[wave] = sum;
        __syncthreads();
        sum = red[0] + red[1] + red[2] + red[3];
        float inv = 1.0f / sum;
        for (int p = tid; p < P; p += 256) {
            float wv = es[p] * inv;
            es[p] = wv;
            if (y == 0) out2[((size_t)b * T + t) * P + p] = wv;
        }
    }
    __syncthreads();

    // ---- ctx slice y (256 cols of E) + gate matvec + write xbuf ----
    {
        int c4 = tid & 63, q = tid >> 6;
        int src = order[b];
        const float4* f4 = (const float4*)(feat + (size_t)src * P * E) + y * 64 + c4;
        float4 acc = {0.f, 0.f, 0.f, 0.f};
        for (int p = q * 49; p < q * 49 + 49; ++p) {
            float w = es[p];
            float4 fv = f4[(size_t)p * 512];
            acc.x += w * fv.x; acc.y += w * fv.y; acc.z += w * fv.z; acc.w += w * fv.w;
        }
        const float4* g4 = (const float4*)W_gate + y * 64 + c4;
        float4 gacc = {0.f, 0.f, 0.f, 0.f};
        for (int k = q * 64; k < q * 64 + 64; ++k) {
            float hv = hs[k];
            float4 wv = g4[(size_t)k * 512];
            gacc.x += hv * wv.x; gacc.y += hv * wv.y; gacc.z += hv * wv.z; gacc.w += hv * wv.w;
        }
        if (q) { rc[q - 1][c4] = acc; rg[q - 1][c4] = gacc; }
        __syncthreads();
        if (q == 0) {
            #pragma unroll
            for (int j = 0; j < 3; ++j) {
                float4 a = rc[j][c4], g = rg[j][c4];
                acc.x += a.x; acc.y += a.y; acc.z += a.z; acc.w += a.w;
                gacc.x += g.x; gacc.y += g.y; gacc.z += g.z; gacc.w += g.w;
            }
            float4 gb = *(const float4*)(b_gate + (y * 64 + c4) * 4);
            float4 o;
            o.x = acc.x / (1.f + expf(-(gacc.x + gb.x)));
            o.y = acc.y / (1.f + expf(-(gacc.y + gb.y)));
            o.z = acc.z / (1.f + expf(-(gacc.z + gb.z)));
            o.w = acc.w / (1.f + expf(-(gacc.w + gb.w)));
            *(float4*)(xbuf + (size_t)b * KX + EM + (y * 64 + c4) * 4) = o;
        }
    }
}

// ---------------- final pointwise only (t == T): produce hn_all[T-1] ----------------
__global__ __launch_bounds__(256) void pw_final(const int* __restrict__ target,
                                                const float* __restrict__ gpart,
                                                const float* __restrict__ b_ih,
                                                const float* __restrict__ b_hh,
                                                const float* __restrict__ c_rd,
                                                float* __restrict__ hn_all) {
    int b = blockIdx.x;
    if (target[b] < T) return;   // need tgt > T-1
    int d = threadIdx.x;
    float gi = b_ih[d] + b_hh[d];
    float gf = b_ih[D + d] + b_hh[D + d];
    float gg = b_ih[2 * D + d] + b_hh[2 * D + d];
    float go = b_ih[3 * D + d] + b_hh[3 * D + d];
    #pragma unroll
    for (int ky = 0; ky < 8; ++ky) {
        const float* gp = gpart + ((size_t)ky * B + b) * 1024;
        gi += gp[d];
        gf += gp[D + d];
        gg += gp[2 * D + d];
        go += gp[3 * D + d];
    }
    float c_old = c_rd[b * D + d];
    float si = 1.f / (1.f + expf(-gi));
    float sf = 1.f / (1.f + expf(-gf));
    float so = 1.f / (1.f + expf(-go));
    float cn = sf * c_old + si * tanhf(gg);
    float hnv = so * tanhf(cn);
    hn_all[((size_t)(T - 1) * B + b) * D + d] = hnv;
}

// ---------------- gate GEMM: K split 8-way ----------------
__global__ __launch_bounds__(256) void lstm_gemm(const float* __restrict__ xbuf,
                                                 const float* __restrict__ W_ih,
                                                 const float* __restrict__ W_hh,
                                                 float* __restrict__ gpart) {
    __shared__ float As[32][68];
    __shared__ float Bs[32][64];
    int cb = blockIdx.x;   // 0..15
    int ky = blockIdx.y;   // 0..7
    int tid = threadIdx.x;
    int tx = tid & 15, ty = tid >> 4;
    float acc[4][4] = {};
    int k0base = ky * 320;
    for (int k0 = k0base; k0 < k0base + 320; k0 += 32) {
        #pragma unroll
        for (int q = 0; q < 2; ++q) {
            int idx = q * 256 + tid;
            int kv = idx & 7, m = idx >> 3;
            float4 v = *(const float4*)(xbuf + (size_t)m * KX + k0 + kv * 4);
            As[kv * 4 + 0][m] = v.x;
            As[kv * 4 + 1][m] = v.y;
            As[kv * 4 + 2][m] = v.z;
            As[kv * 4 + 3][m] = v.w;
        }
        #pragma unroll
        for (int q = 0; q < 2; ++q) {
            int idx = q * 256 + tid;
            int n4 = idx & 15, kk = idx >> 4;
            int k = k0 + kk;
            const float* src = (k < EM + E) ? (W_ih + (size_t)k * 1024)
                                            : (W_hh + (size_t)(k - EM - E) * 1024);
            float4 v = *(const float4*)(src + cb * 64 + n4 * 4);
            *(float4*)&Bs[kk][n4 * 4] = v;
        }
        __syncthreads();
        #pragma unroll
        for (int kk = 0; kk < 32; ++kk) {
            float4 av = *(const float4*)&As[kk][ty * 4];
            float4 bv = *(const float4*)&Bs[kk][tx * 4];
            acc[0][0] += av.x * bv.x; acc[0][1] += av.x * bv.y; acc[0][2] += av.x * bv.z; acc[0][3] += av.x * bv.w;
            acc[1][0] += av.y * bv.x; acc[1][1] += av.y * bv.y; acc[1][2] += av.y * bv.z; acc[1][3] += av.y * bv.w;
            acc[2][0] += av.z * bv.x; acc[2][1] += av.z * bv.y; acc[2][2] += av.z * bv.z; acc[2][3] += av.z * bv.w;
            acc[3][0] += av.w * bv.x; acc[3][1] += av.w * bv.y; acc[3][2] += av.w * bv.z; acc[3][3] += av.w * bv.w;
        }
        __syncthreads();
    }
    #pragma unroll
    for (int a = 0; a < 4; ++a) {
        int bidx = ty * 4 + a;
        float4 o = {acc[a][0], acc[a][1], acc[a][2], acc[a][3]};
        *(float4*)(gpart + ((size_t)ky * B + bidx) * 1024 + cb * 64 + tx * 4) = o;
    }
}

// ---------------- batched head over all t: grid (157, 62) ----------------
__global__ __launch_bounds__(256) void head_batch(const float* __restrict__ hn_all,
                                                  const float* __restrict__ W_head,
                                                  const float* __restrict__ b_head,
                                                  const int* __restrict__ target,
                                                  float* __restrict__ out1) {
    int by = blockIdx.y;
    int t = by >> 1, qh = by & 1;
    if (target[qh * 32] <= t) return;   // sorted: whole 32-row tile inactive
    __shared__ float hs[32][260];
    int cb = blockIdx.x;
    int tid = threadIdx.x;
    #pragma unroll
    for (int q = 0; q < 8; ++q) {
        int idx = q * 256 + tid;
        int r = idx >> 6, kq = idx & 63;
        float4 v = *(const float4*)(hn_all + ((size_t)t * B + qh * 32 + r) * D + kq * 4);
        *(float4*)&hs[r][kq * 4] = v;
    }
    __syncthreads();
    int col = cb * 64 + (tid & 63);
    int rgrp = (tid >> 6) * 8;
    if (col < V) {
        float acc[8] = {};
        for (int kq = 0; kq < 64; ++kq) {
            float w0 = W_head[(size_t)(kq * 4 + 0) * V + col];
            float w1 = W_head[(size_t)(kq * 4 + 1) * V + col];
            float w2 = W_head[(size_t)(kq * 4 + 2) * V + col];
            float w3 = W_head[(size_t)(kq * 4 + 3) * V + col];
            #pragma unroll
            for (int r = 0; r < 8; ++r) {
                float4 hv = *(const float4*)&hs[rgrp + r][kq * 4];
                acc[r] += hv.x * w0 + hv.y * w1 + hv.z * w2 + hv.w * w3;
            }
        }
        float bh_ = b_head[col];
        #pragma unroll
        for (int r = 0; r < 8; ++r) {
            int brow = qh * 32 + rgrp + r;
            if (target[brow] > t)
                out1[((size_t)brow * T + t) * V + col] = acc[r] + bh_;
        }
    }
}

extern "C" void kernel_launch(void* const* d_in, const int* in_sizes, int n_in,
                              void* d_out, int out_size, void* d_ws, size_t ws_size,
                              hipStream_t stream) {
    const float* feat   = (const float*)d_in[0];
    const int*   tok    = (const int*)d_in[1];
    const int*   clen   = (const int*)d_in[2];
    const float* Wf     = (const float*)d_in[3];
    const float* bf     = (const float*)d_in[4];
    const float* Wh     = (const float*)d_in[5];
    const float* bh     = (const float*)d_in[6];
    const float* We     = (const float*)d_in[7];
    const float* be     = (const float*)d_in[8];
    const float* emb    = (const float*)d_in[9];
    const float* W_ih   = (const float*)d_in[10];
    const float* b_ih   = (const float*)d_in[11];
    const float* W_hh   = (const float*)d_in[12];
    const float* b_hh   = (const float*)d_in[13];
    const float* W_hid  = (const float*)d_in[14];
    const float* b_hid  = (const float*)d_in[15];
    const float* W_cell = (const float*)d_in[16];
    const float* b_cell = (const float*)d_in[17];
    const float* W_gate = (const float*)d_in[18];
    const float* b_gate = (const float*)d_in[19];
    const float* W_head = (const float*)d_in[20];
    const float* b_head = (const float*)d_in[21];

    float* out1 = (float*)d_out;
    float* out2 = out1 + (size_t)B * T * V;

    char* wp = (char*)d_ws;
    int* order   = (int*)wp;           wp += 256;
    int* targetp = (int*)wp;           wp += 256;
    float* fe    = (float*)wp;         wp += (size_t)B * P * H_ * sizeof(float);
    float* hbuf  = (float*)wp;         wp += (size_t)B * D * sizeof(float);
    float* cbuf  = (float*)wp;         wp += (size_t)2 * B * D * sizeof(float);   // double-buffered
    float* xbuf  = (float*)wp;         wp += (size_t)B * KX * sizeof(float);
    float* gpart = (float*)wp;         wp += (size_t)8 * B * 1024 * sizeof(float);
    float* mean_feat = (float*)wp;     wp += (size_t)B * E * sizeof(float);
    float* hpart = (float*)wp;         wp += (size_t)8 * B * 512 * sizeof(float);
    float* hn_all = (float*)wp;        wp += (size_t)T * B * D * sizeof(float);

    hipMemsetAsync(d_out, 0, (size_t)out_size * sizeof(float), stream);

    sort_kernel<<<1, 64, 0, stream>>>(clen, order, targetp);
    mean_kernel<<<dim3(B, E / 256), 256, 0, stream>>>(feat, order, mean_feat);
    h0c0_gemm<<<dim3(8, 8), 256, 0, stream>>>(mean_feat, W_hid, W_cell, hpart);
    h0c0_reduce<<<B, 256, 0, stream>>>(hpart, b_hid, b_cell, emb, tok, order,
                                       hbuf, cbuf, xbuf);    // c0 -> cbuf[0]
    fe_gemm<<<dim3(196, 4), 256, 0, stream>>>(feat, order, Wf, bf, fe);

    // ---- per-step loop: 2 kernels/step ----
    // attn_ctx(t) reads c from cbuf[(t+1)&1], writes cbuf[t&1]
    for (int t = 0; t < T; ++t) {
        attn_ctx<<<dim3(B, 8), 256, 0, stream>>>(targetp, gpart, b_ih, b_hh, emb, tok,
                                                 order, Wh, bh, We, be, fe, hbuf,
                                                 cbuf + (size_t)((t + 1) & 1) * B * D,
                                                 cbuf + (size_t)(t & 1) * B * D,
                                                 hn_all, xbuf, out2,
                                                 feat, W_gate, b_gate, t);
        lstm_gemm<<<dim3(16, 8), 256, 0, stream>>>(xbuf, W_ih, W_hh, gpart);
    }
    // final pointwise (t == T): c read parity = (T+1)&1 = 0
    pw_final<<<B, 256, 0, stream>>>(targetp, gpart, b_ih, b_hh, cbuf, hn_all);

    head_batch<<<dim3(157, 62), 256, 0, stream>>>(hn_all, W_head, b_head, targetp, out1);
}

// Round 4
// 2628.318 us; speedup vs baseline: 4.0374x; 1.0395x over previous
//
#include <hip/hip_runtime.h>
#include <math.h>

#define B 64
#define P 196
#define E 2048
#define D 256
#define H_ 256
#define EM 256
#define V 10000
#define L 32
#define T 31
#define KX2 2304   // E + D  (ctx | h) -- emb contribution precomputed in Gemb
#define NKY 18     // lstm split-K factor: 2304 = 18 * 128

// ---------------- sort: stable argsort descending by length ----------------
__global__ __launch_bounds__(64) void sort_kernel(const int* __restrict__ clen,
                                                  int* __restrict__ order,
                                                  int* __restrict__ target) {
    __shared__ int len_s[B];
    int i = threadIdx.x;
    len_s[i] = clen[i];
    __syncthreads();
    int li = len_s[i];
    int rank = 0;
    for (int j = 0; j < B; ++j) {
        int lj = len_s[j];
        if (lj > li || (lj == li && j < i)) rank++;
    }
    order[rank] = i;
    target[rank] = li - 1;
}

// ---------------- mean_feat[b][e] = mean_p feat[src][p][e] ----------------
__global__ __launch_bounds__(256) void mean_kernel(const float* __restrict__ feat,
                                                   const int* __restrict__ order,
                                                   float* __restrict__ mean_feat) {
    int b = blockIdx.x;
    int e = blockIdx.y * 256 + threadIdx.x;
    int src = order[b];
    const float* fp = feat + (size_t)src * P * E + e;
    float acc = 0.f;
    #pragma unroll 4
    for (int p = 0; p < P; ++p) acc += fp[(size_t)p * E];
    mean_feat[b * E + e] = acc * (1.0f / (float)P);
}

// ---------------- h0c0 as split-K GEMM: hpart[ky][64][512] ----------------
__global__ __launch_bounds__(256) void h0c0_gemm(const float* __restrict__ mean_feat,
                                                 const float* __restrict__ W_hid,
                                                 const float* __restrict__ W_cell,
                                                 float* __restrict__ hpart) {
    __shared__ float As[32][68];
    __shared__ float Bs[32][64];
    int cb = blockIdx.x;   // 0..7
    int ky = blockIdx.y;   // 0..7
    int tid = threadIdx.x;
    int tx = tid & 15, ty = tid >> 4;
    const float* Wsrc;
    int ncol0;
    if (cb < 4) { Wsrc = W_hid;  ncol0 = cb * 64; }
    else        { Wsrc = W_cell; ncol0 = (cb - 4) * 64; }
    float acc[4][4] = {};
    for (int k0 = ky * 256; k0 < ky * 256 + 256; k0 += 32) {
        #pragma unroll
        for (int q = 0; q < 2; ++q) {
            int idx = q * 256 + tid;
            int kv = idx & 7, m = idx >> 3;
            float4 v = *(const float4*)(mean_feat + (size_t)m * E + k0 + kv * 4);
            As[kv * 4 + 0][m] = v.x;
            As[kv * 4 + 1][m] = v.y;
            As[kv * 4 + 2][m] = v.z;
            As[kv * 4 + 3][m] = v.w;
        }
        #pragma unroll
        for (int q = 0; q < 2; ++q) {
            int idx = q * 256 + tid;
            int n4 = idx & 15, kk = idx >> 4;
            float4 v = *(const float4*)(Wsrc + (size_t)(k0 + kk) * 256 + ncol0 + n4 * 4);
            *(float4*)&Bs[kk][n4 * 4] = v;
        }
        __syncthreads();
        #pragma unroll
        for (int kk = 0; kk < 32; ++kk) {
            float4 av = *(const float4*)&As[kk][ty * 4];
            float4 bv = *(const float4*)&Bs[kk][tx * 4];
            acc[0][0] += av.x * bv.x; acc[0][1] += av.x * bv.y; acc[0][2] += av.x * bv.z; acc[0][3] += av.x * bv.w;
            acc[1][0] += av.y * bv.x; acc[1][1] += av.y * bv.y; acc[1][2] += av.y * bv.z; acc[1][3] += av.y * bv.w;
            acc[2][0] += av.z * bv.x; acc[2][1] += av.z * bv.y; acc[2][2] += av.z * bv.z; acc[2][3] += av.z * bv.w;
            acc[3][0] += av.w * bv.x; acc[3][1] += av.w * bv.y; acc[3][2] += av.w * bv.z; acc[3][3] += av.w * bv.w;
        }
        __syncthreads();
    }
    #pragma unroll
    for (int a = 0; a < 4; ++a) {
        int row = ty * 4 + a;
        float4 o = {acc[a][0], acc[a][1], acc[a][2], acc[a][3]};
        *(float4*)(hpart + ((size_t)ky * B + row) * 512 + cb * 64 + tx * 4) = o;
    }
}

// ---------------- h0c0 reduce: sum partials, add bias, init h/c/xbuf(h) ----------------
__global__ __launch_bounds__(256) void h0c0_reduce(const float* __restrict__ hpart,
                                                   const float* __restrict__ b_hid,
                                                   const float* __restrict__ b_cell,
                                                   float* __restrict__ h,
                                                   float* __restrict__ c0,
                                                   float* __restrict__ xbuf) {
    int b = blockIdx.x, tid = threadIdx.x;
    float s0 = 0.f, s1 = 0.f;
    #pragma unroll
    for (int ky = 0; ky < 8; ++ky) {
        const float* hp = hpart + ((size_t)ky * B + b) * 512;
        s0 += hp[tid];
        s1 += hp[256 + tid];
    }
    float h0 = s0 + b_hid[tid];
    h[b * D + tid] = h0;
    c0[b * D + tid] = s1 + b_cell[tid];
    xbuf[(size_t)b * KX2 + 2048 + tid] = h0;
}

// ---------------- Gemb[t][b][n] = emb[tok[order[b],t]] @ W_ih[0:256]; grid (16, 31) ----------------
__global__ __launch_bounds__(256) void gemb_gemm(const float* __restrict__ emb,
                                                 const int* __restrict__ cap_tok,
                                                 const int* __restrict__ order,
                                                 const float* __restrict__ W_ih,
                                                 float* __restrict__ Gemb) {
    __shared__ float As[32][68];
    __shared__ float Bs[32][64];
    __shared__ int srcTok[64];
    int cb = blockIdx.x;   // 0..15
    int t  = blockIdx.y;   // 0..30
    int tid = threadIdx.x;
    if (tid < 64) srcTok[tid] = cap_tok[order[tid] * L + t];
    __syncthreads();
    int tx = tid & 15, ty = tid >> 4;
    float acc[4][4] = {};
    for (int k0 = 0; k0 < EM; k0 += 32) {
        #pragma unroll
        for (int q = 0; q < 2; ++q) {
            int idx = q * 256 + tid;
            int kv = idx & 7, m = idx >> 3;
            float4 v = *(const float4*)(emb + (size_t)srcTok[m] * EM + k0 + kv * 4);
            As[kv * 4 + 0][m] = v.x;
            As[kv * 4 + 1][m] = v.y;
            As[kv * 4 + 2][m] = v.z;
            As[kv * 4 + 3][m] = v.w;
        }
        #pragma unroll
        for (int q = 0; q < 2; ++q) {
            int idx = q * 256 + tid;
            int n4 = idx & 15, kk = idx >> 4;
            float4 v = *(const float4*)(W_ih + (size_t)(k0 + kk) * 1024 + cb * 64 + n4 * 4);
            *(float4*)&Bs[kk][n4 * 4] = v;
        }
        __syncthreads();
        #pragma unroll
        for (int kk = 0; kk < 32; ++kk) {
            float4 av = *(const float4*)&As[kk][ty * 4];
            float4 bv = *(const float4*)&Bs[kk][tx * 4];
            acc[0][0] += av.x * bv.x; acc[0][1] += av.x * bv.y; acc[0][2] += av.x * bv.z; acc[0][3] += av.x * bv.w;
            acc[1][0] += av.y * bv.x; acc[1][1] += av.y * bv.y; acc[1][2] += av.y * bv.z; acc[1][3] += av.y * bv.w;
            acc[2][0] += av.z * bv.x; acc[2][1] += av.z * bv.y; acc[2][2] += av.z * bv.z; acc[2][3] += av.z * bv.w;
            acc[3][0] += av.w * bv.x; acc[3][1] += av.w * bv.y; acc[3][2] += av.w * bv.z; acc[3][3] += av.w * bv.w;
        }
        __syncthreads();
    }
    #pragma unroll
    for (int a = 0; a < 4; ++a) {
        int row = ty * 4 + a;
        float4 o = {acc[a][0], acc[a][1], acc[a][2], acc[a][3]};
        *(float4*)(Gemb + ((size_t)t * B + row) * 1024 + cb * 64 + tx * 4) = o;
    }
}

// ---------------- fe partial GEMM: K split 2-way in one dispatch; grid (196, 4, 2) ----------------
__global__ __launch_bounds__(256) void fe_gemm(const float* __restrict__ feat,
                                               const int* __restrict__ order,
                                               const float* __restrict__ Wf,
                                               float* __restrict__ dst0,
                                               float* __restrict__ dst1) {
    __shared__ float As[32][68];
    __shared__ float Bs[32][64];
    __shared__ int srcRow[64];
    int rowBlock = blockIdx.x;   // 0..195
    int colBlock = blockIdx.y;   // 0..3
    int kz = blockIdx.z;         // 0..1
    int tid = threadIdx.x;
    if (tid < 64) {
        int gr = rowBlock * 64 + tid;
        int b = gr / P, p = gr % P;
        srcRow[tid] = order[b] * P + p;
    }
    __syncthreads();
    int tx = tid & 15, ty = tid >> 4;
    float acc[4][4] = {};
    for (int k0 = kz * 1024; k0 < kz * 1024 + 1024; k0 += 32) {
        #pragma unroll
        for (int q = 0; q < 2; ++q) {
            int idx = q * 256 + tid;
            int kv = idx & 7, m = idx >> 3;
            float4 v = *(const float4*)(feat + (size_t)srcRow[m] * E + k0 + kv * 4);
            As[kv * 4 + 0][m] = v.x;
            As[kv * 4 + 1][m] = v.y;
            As[kv * 4 + 2][m] = v.z;
            As[kv * 4 + 3][m] = v.w;
        }
        {
            int n4 = tid & 15, kk = tid >> 4;   // kk 0..15
            float4 v = *(const float4*)(Wf + (size_t)(k0 + kk) * H_ + colBlock * 64 + n4 * 4);
            *(float4*)&Bs[kk][n4 * 4] = v;
            int kk2 = kk + 16;
            float4 v2 = *(const float4*)(Wf + (size_t)(k0 + kk2) * H_ + colBlock * 64 + n4 * 4);
            *(float4*)&Bs[kk2][n4 * 4] = v2;
        }
        __syncthreads();
        #pragma unroll
        for (int kk = 0; kk < 32; ++kk) {
            float4 av = *(const float4*)&As[kk][ty * 4];
            float4 bv = *(const float4*)&Bs[kk][tx * 4];
            acc[0][0] += av.x * bv.x; acc[0][1] += av.x * bv.y; acc[0][2] += av.x * bv.z; acc[0][3] += av.x * bv.w;
            acc[1][0] += av.y * bv.x; acc[1][1] += av.y * bv.y; acc[1][2] += av.y * bv.z; acc[1][3] += av.y * bv.w;
            acc[2][0] += av.z * bv.x; acc[2][1] += av.z * bv.y; acc[2][2] += av.z * bv.z; acc[2][3] += av.z * bv.w;
            acc[3][0] += av.w * bv.x; acc[3][1] += av.w * bv.y; acc[3][2] += av.w * bv.z; acc[3][3] += av.w * bv.w;
        }
        __syncthreads();
    }
    float* dst = kz ? dst1 : dst0;
    #pragma unroll
    for (int a = 0; a < 4; ++a) {
        int gr = rowBlock * 64 + ty * 4 + a;
        float4 o = {acc[a][0], acc[a][1], acc[a][2], acc[a][3]};
        *(float4*)(dst + (size_t)gr * H_ + colBlock * 64 + tx * 4) = o;
    }
}

// ---------------- fe reduce: fe = part0(in fe) + part1 + bias ----------------
__global__ __launch_bounds__(256) void fe_reduce(float* __restrict__ fe,
                                                 const float* __restrict__ fepart1,
                                                 const float* __restrict__ bf) {
    size_t f4 = (size_t)blockIdx.x * 256 + threadIdx.x;
    int col4 = (int)(f4 & 63);
    float4 a = *(const float4*)(fe + f4 * 4);
    float4 b = *(const float4*)(fepart1 + f4 * 4);
    float4 bias = *(const float4*)(bf + col4 * 4);
    float4 o = {a.x + b.x + bias.x, a.y + b.y + bias.y,
                a.z + b.z + bias.z, a.w + b.w + bias.w};
    *(float4*)(fe + f4 * 4) = o;
}

// ============ fused per-step kernel: pointwise + attention + ctx, grid (B,8) ============
__global__ __launch_bounds__(256) void attn_ctx(const int* __restrict__ target,
                                                const float* __restrict__ gpart,
                                                const float* __restrict__ Gemb,
                                                const float* __restrict__ b_ih,
                                                const float* __restrict__ b_hh,
                                                const int* __restrict__ order,
                                                const float* __restrict__ Wh,
                                                const float* __restrict__ bh,
                                                const float* __restrict__ We,
                                                const float* __restrict__ be,
                                                const float* __restrict__ fe,
                                                const float* __restrict__ h0,
                                                const float* __restrict__ c_rd,
                                                float* __restrict__ c_wr,
                                                float* __restrict__ hn_all,
                                                float* __restrict__ xbuf,
                                                float* __restrict__ out2,
                                                const float* __restrict__ feat,
                                                const float* __restrict__ W_gate,
                                                const float* __restrict__ b_gate,
                                                int t) {
    int b = blockIdx.x, y = blockIdx.y, tid = threadIdx.x;
    int tgt = target[b];
    bool pw_active = (t > 0) && (tgt > t - 1);
    bool at_active = (tgt > t);
    if (!at_active && !(pw_active && y == 0)) return;

    __shared__ float hs[D];
    __shared__ float hes[D];
    __shared__ float es[200];
    __shared__ float red[4];
    __shared__ float4 rc[3][64];
    __shared__ float4 rg[3][64];

    if (pw_active) {
        int d = tid;
        const float* ge = Gemb + ((size_t)(t - 1) * B + b) * 1024;
        float gi = b_ih[d] + b_hh[d] + ge[d];
        float gf = b_ih[D + d] + b_hh[D + d] + ge[D + d];
        float gg = b_ih[2 * D + d] + b_hh[2 * D + d] + ge[2 * D + d];
        float go = b_ih[3 * D + d] + b_hh[3 * D + d] + ge[3 * D + d];
        #pragma unroll
        for (int ky = 0; ky < NKY; ++ky) {
            const float* gp = gpart + ((size_t)ky * B + b) * 1024;
            gi += gp[d];
            gf += gp[D + d];
            gg += gp[2 * D + d];
            go += gp[3 * D + d];
        }
        float c_old = c_rd[b * D + d];
        float si = 1.f / (1.f + expf(-gi));
        float sf = 1.f / (1.f + expf(-gf));
        float so = 1.f / (1.f + expf(-go));
        float cn = sf * c_old + si * tanhf(gg);
        float hnv = so * tanhf(cn);
        hs[d] = hnv;
        if (y == 0) {
            c_wr[b * D + d] = cn;
            hn_all[((size_t)(t - 1) * B + b) * D + d] = hnv;
            xbuf[(size_t)b * KX2 + 2048 + d] = hnv;
        }
    } else {
        hs[tid] = h0[b * D + tid];   // only at t == 0
    }
    __syncthreads();
    if (!at_active) return;

    // he = hs @ Wh + bh (4 partial accumulators)
    {
        float a0 = 0.f, a1 = 0.f, a2 = 0.f, a3 = 0.f;
        #pragma unroll 4
        for (int k = 0; k < D; k += 4) {
            a0 += hs[k]     * Wh[(size_t)k * H_ + tid];
            a1 += hs[k + 1] * Wh[(size_t)(k + 1) * H_ + tid];
            a2 += hs[k + 2] * Wh[(size_t)(k + 2) * H_ + tid];
            a3 += hs[k + 3] * Wh[(size_t)(k + 3) * H_ + tid];
        }
        hes[tid] = (a0 + a1) + (a2 + a3) + bh[tid];
    }
    __syncthreads();

    int wave = tid >> 6, lane = tid & 63;
    {
        float4 he4 = *(const float4*)&hes[lane * 4];
        float4 we4 = *(const float4*)(We + lane * 4);
        for (int p = wave; p < P; p += 4) {
            float4 fv = *(const float4*)(fe + ((size_t)b * P + p) * H_ + lane * 4);
            float x0 = fv.x + he4.x; x0 = x0 > 0.f ? x0 : 0.f;
            float x1 = fv.y + he4.y; x1 = x1 > 0.f ? x1 : 0.f;
            float x2 = fv.z + he4.z; x2 = x2 > 0.f ? x2 : 0.f;
            float x3 = fv.w + he4.w; x3 = x3 > 0.f ? x3 : 0.f;
            float s = x0 * we4.x + x1 * we4.y + x2 * we4.z + x3 * we4.w;
            #pragma unroll
            for (int off = 32; off > 0; off >>= 1) s += __shfl_down(s, off);
            if (lane == 0) es[p] = s + be[0];
        }
    }
    __syncthreads();
    {
        float mx = -1e30f;
        for (int p = tid; p < P; p += 256) mx = fmaxf(mx, es[p]);
        #pragma unroll
        for (int off = 32; off > 0; off >>= 1) mx = fmaxf(mx, __shfl_down(mx, off));
        if (lane == 0) red[wave] = mx;
        __syncthreads();
        mx = fmaxf(fmaxf(red[0], red[1]), fmaxf(red[2], red[3]));
        __syncthreads();
        float sum = 0.f;
        for (int p = tid; p < P; p += 256) {
            float ex = expf(es[p] - mx);
            es[p] = ex;
            sum += ex;
        }
        #pragma unroll
        for (int off = 32; off > 0; off >>= 1) sum += __shfl_down(sum, off);
        if (lane == 0) red[wave] = sum;
        __syncthreads();
        sum = red[0] + red[1] + red[2] + red[3];
        float inv = 1.0f / sum;
        for (int p = tid; p < P; p += 256) {
            float wv = es[p] * inv;
            es[p] = wv;
            if (y == 0) out2[((size_t)b * T + t) * P + p] = wv;
        }
    }
    __syncthreads();

    {
        int c4 = tid & 63, q = tid >> 6;
        int src = order[b];
        const float4* f4 = (const float4*)(feat + (size_t)src * P * E) + y * 64 + c4;
        float4 acc = {0.f, 0.f, 0.f, 0.f};
        for (int p = q * 49; p < q * 49 + 49; ++p) {
            float w = es[p];
            float4 fv = f4[(size_t)p * 512];
            acc.x += w * fv.x; acc.y += w * fv.y; acc.z += w * fv.z; acc.w += w * fv.w;
        }
        const float4* g4 = (const float4*)W_gate + y * 64 + c4;
        float4 gacc = {0.f, 0.f, 0.f, 0.f};
        for (int k = q * 64; k < q * 64 + 64; ++k) {
            float hv = hs[k];
            float4 wv = g4[(size_t)k * 512];
            gacc.x += hv * wv.x; gacc.y += hv * wv.y; gacc.z += hv * wv.z; gacc.w += hv * wv.w;
        }
        if (q) { rc[q - 1][c4] = acc; rg[q - 1][c4] = gacc; }
        __syncthreads();
        if (q == 0) {
            #pragma unroll
            for (int j = 0; j < 3; ++j) {
                float4 a = rc[j][c4], g = rg[j][c4];
                acc.x += a.x; acc.y += a.y; acc.z += a.z; acc.w += a.w;
                gacc.x += g.x; gacc.y += g.y; gacc.z += g.z; gacc.w += g.w;
            }
            float4 gb = *(const float4*)(b_gate + (y * 64 + c4) * 4);
            float4 o;
            o.x = acc.x / (1.f + expf(-(gacc.x + gb.x)));
            o.y = acc.y / (1.f + expf(-(gacc.y + gb.y)));
            o.z = acc.z / (1.f + expf(-(gacc.z + gb.z)));
            o.w = acc.w / (1.f + expf(-(gacc.w + gb.w)));
            *(float4*)(xbuf + (size_t)b * KX2 + (y * 64 + c4) * 4) = o;
        }
    }
}

// ---------------- final pointwise only (t == T) ----------------
__global__ __launch_bounds__(256) void pw_final(const int* __restrict__ target,
                                                const float* __restrict__ gpart,
                                                const float* __restrict__ Gemb,
                                                const float* __restrict__ b_ih,
                                                const float* __restrict__ b_hh,
                                                const float* __restrict__ c_rd,
                                                float* __restrict__ hn_all) {
    int b = blockIdx.x;
    if (target[b] < T) return;
    int d = threadIdx.x;
    const float* ge = Gemb + ((size_t)(T - 1) * B + b) * 1024;
    float gi = b_ih[d] + b_hh[d] + ge[d];
    float gf = b_ih[D + d] + b_hh[D + d] + ge[D + d];
    float gg = b_ih[2 * D + d] + b_hh[2 * D + d] + ge[2 * D + d];
    float go = b_ih[3 * D + d] + b_hh[3 * D + d] + ge[3 * D + d];
    #pragma unroll
    for (int ky = 0; ky < NKY; ++ky) {
        const float* gp = gpart + ((size_t)ky * B + b) * 1024;
        gi += gp[d];
        gf += gp[D + d];
        gg += gp[2 * D + d];
        go += gp[3 * D + d];
    }
    float c_old = c_rd[b * D + d];
    float si = 1.f / (1.f + expf(-gi));
    float sf = 1.f / (1.f + expf(-gf));
    float so = 1.f / (1.f + expf(-go));
    float cn = sf * c_old + si * tanhf(gg);
    float hnv = so * tanhf(cn);
    hn_all[((size_t)(T - 1) * B + b) * D + d] = hnv;
}

// ---------------- gate GEMM: K = 2304 split 18-way; grid (16, 18) ----------------
// xbuf per batch: [ctx(2048) | h(256)]; weights: W_ih rows 256..2303 for ctx, W_hh for h.
__global__ __launch_bounds__(256) void lstm_gemm(const float* __restrict__ xbuf,
                                                 const float* __restrict__ W_ih,
                                                 const float* __restrict__ W_hh,
                                                 float* __restrict__ gpart) {
    __shared__ float As[32][68];
    __shared__ float Bs[32][64];
    int cb = blockIdx.x;   // 0..15
    int ky = blockIdx.y;   // 0..17
    int tid = threadIdx.x;
    int tx = tid & 15, ty = tid >> 4;
    float acc[4][4] = {};
    int k0base = ky * 128;
    for (int k0 = k0base; k0 < k0base + 128; k0 += 32) {
        #pragma unroll
        for (int q = 0; q < 2; ++q) {
            int idx = q * 256 + tid;
            int kv = idx & 7, m = idx >> 3;
            float4 v = *(const float4*)(xbuf + (size_t)m * KX2 + k0 + kv * 4);
            As[kv * 4 + 0][m] = v.x;
            As[kv * 4 + 1][m] = v.y;
            As[kv * 4 + 2][m] = v.z;
            As[kv * 4 + 3][m] = v.w;
        }
        #pragma unroll
        for (int q = 0; q < 2; ++q) {
            int idx = q * 256 + tid;
            int n4 = idx & 15, kk = idx >> 4;
            int k = k0 + kk;
            const float* src = (k < E) ? (W_ih + (size_t)(EM + k) * 1024)
                                       : (W_hh + (size_t)(k - E) * 1024);
            float4 v = *(const float4*)(src + cb * 64 + n4 * 4);
            *(float4*)&Bs[kk][n4 * 4] = v;
        }
        __syncthreads();
        #pragma unroll
        for (int kk = 0; kk < 32; ++kk) {
            float4 av = *(const float4*)&As[kk][ty * 4];
            float4 bv = *(const float4*)&Bs[kk][tx * 4];
            acc[0][0] += av.x * bv.x; acc[0][1] += av.x * bv.y; acc[0][2] += av.x * bv.z; acc[0][3] += av.x * bv.w;
            acc[1][0] += av.y * bv.x; acc[1][1] += av.y * bv.y; acc[1][2] += av.y * bv.z; acc[1][3] += av.y * bv.w;
            acc[2][0] += av.z * bv.x; acc[2][1] += av.z * bv.y; acc[2][2] += av.z * bv.z; acc[2][3] += av.z * bv.w;
            acc[3][0] += av.w * bv.x; acc[3][1] += av.w * bv.y; acc[3][2] += av.w * bv.z; acc[3][3] += av.w * bv.w;
        }
        __syncthreads();
    }
    #pragma unroll
    for (int a = 0; a < 4; ++a) {
        int bidx = ty * 4 + a;
        float4 o = {acc[a][0], acc[a][1], acc[a][2], acc[a][3]};
        *(float4*)(gpart + ((size_t)ky * B + bidx) * 1024 + cb * 64 + tx * 4) = o;
    }
}

// ---------------- batched head: grid (157, 8); t-chunk of 8 per block ----------------
__global__ __launch_bounds__(256) void head_batch(const float* __restrict__ hn_all,
                                                  const float* __restrict__ W_head,
                                                  const float* __restrict__ b_head,
                                                  const int* __restrict__ target,
                                                  float* __restrict__ out1) {
    int by = blockIdx.y;
    int qh = by >> 2, tc = by & 3;
    int t0 = tc * 8;
    if (target[qh * 32] <= t0) return;
    __shared__ float hs[32][260];
    int cb = blockIdx.x;
    int tid = threadIdx.x;
    int col = cb * 64 + (tid & 63);
    int rgrp = (tid >> 6) * 8;
    float bh_ = (col < V) ? b_head[col] : 0.f;
    for (int t = t0; t < t0 + 8 && t < T; ++t) {
        if (target[qh * 32] <= t) break;
        __syncthreads();
        #pragma unroll
        for (int q = 0; q < 8; ++q) {
            int idx = q * 256 + tid;
            int r = idx >> 6, kq = idx & 63;
            float4 v = *(const float4*)(hn_all + ((size_t)t * B + qh * 32 + r) * D + kq * 4);
            *(float4*)&hs[r][kq * 4] = v;
        }
        __syncthreads();
        if (col < V) {
            float acc[8] = {};
            for (int kq = 0; kq < 64; ++kq) {
                float w0 = W_head[(size_t)(kq * 4 + 0) * V + col];
                float w1 = W_head[(size_t)(kq * 4 + 1) * V + col];
                float w2 = W_head[(size_t)(kq * 4 + 2) * V + col];
                float w3 = W_head[(size_t)(kq * 4 + 3) * V + col];
                #pragma unroll
                for (int r = 0; r < 8; ++r) {
                    float4 hv = *(const float4*)&hs[rgrp + r][kq * 4];
                    acc[r] += hv.x * w0 + hv.y * w1 + hv.z * w2 + hv.w * w3;
                }
            }
            #pragma unroll
            for (int r = 0; r < 8; ++r) {
                int brow = qh * 32 + rgrp + r;
                if (target[brow] > t)
                    out1[((size_t)brow * T + t) * V + col] = acc[r] + bh_;
            }
        }
    }
}

extern "C" void kernel_launch(void* const* d_in, const int* in_sizes, int n_in,
                              void* d_out, int out_size, void* d_ws, size_t ws_size,
                              hipStream_t stream) {
    const float* feat   = (const float*)d_in[0];
    const int*   tok    = (const int*)d_in[1];
    const int*   clen   = (const int*)d_in[2];
    const float* Wf     = (const float*)d_in[3];
    const float* bf     = (const float*)d_in[4];
    const float* Wh     = (const float*)d_in[5];
    const float* bh     = (const float*)d_in[6];
    const float* We     = (const float*)d_in[7];
    const float* be     = (const float*)d_in[8];
    const float* emb    = (const float*)d_in[9];
    const float* W_ih   = (const float*)d_in[10];
    const float* b_ih   = (const float*)d_in[11];
    const float* W_hh   = (const float*)d_in[12];
    const float* b_hh   = (const float*)d_in[13];
    const float* W_hid  = (const float*)d_in[14];
    const float* b_hid  = (const float*)d_in[15];
    const float* W_cell = (const float*)d_in[16];
    const float* b_cell = (const float*)d_in[17];
    const float* W_gate = (const float*)d_in[18];
    const float* b_gate = (const float*)d_in[19];
    const float* W_head = (const float*)d_in[20];
    const float* b_head = (const float*)d_in[21];

    float* out1 = (float*)d_out;                       // B*T*V floats
    float* out2 = out1 + (size_t)B * T * V;            // B*T*P floats

    // ---- workspace (~17 MB, below proven footprint) ----
    char* wp = (char*)d_ws;
    int* order   = (int*)wp;           wp += 256;
    int* targetp = (int*)wp;           wp += 256;
    float* fe    = (float*)wp;         wp += (size_t)B * P * H_ * sizeof(float);   // K-half-0 partial, then fe
    float* hbuf  = (float*)wp;         wp += (size_t)B * D * sizeof(float);
    float* cbuf  = (float*)wp;         wp += (size_t)2 * B * D * sizeof(float);
    float* xbuf  = (float*)wp;         wp += (size_t)B * KX2 * sizeof(float);
    float* mean_feat = (float*)wp;     wp += (size_t)B * E * sizeof(float);
    float* hpart = (float*)wp;         wp += (size_t)8 * B * 512 * sizeof(float);
    float* hn_all = (float*)wp;        wp += (size_t)T * B * D * sizeof(float);

    // ---- transient scratch inside out1 (79 MB; re-zeroed before head_batch) ----
    float* fepart1 = out1;                              // 3.21M floats, dead after fe_reduce
    float* Gemb    = out1 + (size_t)4 * 1024 * 1024;    // T*B*1024 = 2.03M floats
    float* gpart   = Gemb + (size_t)T * B * 1024;       // NKY*B*1024 = 1.18M floats (ends < 7.3M << B*T*V)

    // zero only out2 now; out1 is scratch until after pw_final
    hipMemsetAsync(out2, 0, (size_t)B * T * P * sizeof(float), stream);

    sort_kernel<<<1, 64, 0, stream>>>(clen, order, targetp);
    mean_kernel<<<dim3(B, E / 256), 256, 0, stream>>>(feat, order, mean_feat);
    h0c0_gemm<<<dim3(8, 8), 256, 0, stream>>>(mean_feat, W_hid, W_cell, hpart);
    h0c0_reduce<<<B, 256, 0, stream>>>(hpart, b_hid, b_cell, hbuf, cbuf, xbuf);
    // fe split-K 2-way, single dispatch (1568 blocks)
    fe_gemm<<<dim3(196, 4, 2), 256, 0, stream>>>(feat, order, Wf, fe, fepart1);
    fe_reduce<<<3136, 256, 0, stream>>>(fe, fepart1, bf);
    gemb_gemm<<<dim3(16, T), 256, 0, stream>>>(emb, tok, order, W_ih, Gemb);

    for (int t = 0; t < T; ++t) {
        attn_ctx<<<dim3(B, 8), 256, 0, stream>>>(targetp, gpart, Gemb, b_ih, b_hh,
                                                 order, Wh, bh, We, be, fe, hbuf,
                                                 cbuf + (size_t)((t + 1) & 1) * B * D,
                                                 cbuf + (size_t)(t & 1) * B * D,
                                                 hn_all, xbuf, out2,
                                                 feat, W_gate, b_gate, t);
        lstm_gemm<<<dim3(16, NKY), 256, 0, stream>>>(xbuf, W_ih, W_hh, gpart);
    }
    pw_final<<<B, 256, 0, stream>>>(targetp, gpart, Gemb, b_ih, b_hh, cbuf, hn_all);

    // scratch in out1 is dead now; zero it so masked entries are 0, then write head
    hipMemsetAsync(out1, 0, (size_t)B * T * V * sizeof(float), stream);
    head_batch<<<dim3(157, 8), 256, 0, stream>>>(hn_all, W_head, b_head, targetp, out1);
}

// Round 6
// 2430.549 us; speedup vs baseline: 4.3660x; 1.0814x over previous
//
#include <hip/hip_runtime.h>
#include <math.h>

#define B 64
#define P 196
#define E 2048
#define D 256
#define H_ 256
#define EM 256
#define V 10000
#define L 32
#define T 31
#define KX2 2304   // E + D  (ctx | h) -- emb contribution precomputed in Gemb
#define NKY 18     // lstm split-K factor: 2304 = 18 * 128
#define FEPART_SZ ((size_t)B * P * H_)   // 3,211,264 floats per fe partial

// ---------------- sort: stable argsort descending by length ----------------
__global__ __launch_bounds__(64) void sort_kernel(const int* __restrict__ clen,
                                                  int* __restrict__ order,
                                                  int* __restrict__ target) {
    __shared__ int len_s[B];
    int i = threadIdx.x;
    len_s[i] = clen[i];
    __syncthreads();
    int li = len_s[i];
    int rank = 0;
    for (int j = 0; j < B; ++j) {
        int lj = len_s[j];
        if (lj > li || (lj == li && j < i)) rank++;
    }
    order[rank] = i;
    target[rank] = li - 1;
}

// ---------------- mean_feat[b][e] = mean_p feat[src][p][e] ----------------
__global__ __launch_bounds__(256) void mean_kernel(const float* __restrict__ feat,
                                                   const int* __restrict__ order,
                                                   float* __restrict__ mean_feat) {
    int b = blockIdx.x;
    int e = blockIdx.y * 256 + threadIdx.x;
    int src = order[b];
    const float* fp = feat + (size_t)src * P * E + e;
    float acc = 0.f;
    #pragma unroll 4
    for (int p = 0; p < P; ++p) acc += fp[(size_t)p * E];
    mean_feat[b * E + e] = acc * (1.0f / (float)P);
}

// ---------------- h0c0 as split-K GEMM: hpart[ky][64][512] ----------------
__global__ __launch_bounds__(256) void h0c0_gemm(const float* __restrict__ mean_feat,
                                                 const float* __restrict__ W_hid,
                                                 const float* __restrict__ W_cell,
                                                 float* __restrict__ hpart) {
    __shared__ float As[32][68];
    __shared__ float Bs[32][64];
    int cb = blockIdx.x;   // 0..7
    int ky = blockIdx.y;   // 0..7
    int tid = threadIdx.x;
    int tx = tid & 15, ty = tid >> 4;
    const float* Wsrc;
    int ncol0;
    if (cb < 4) { Wsrc = W_hid;  ncol0 = cb * 64; }
    else        { Wsrc = W_cell; ncol0 = (cb - 4) * 64; }
    float acc[4][4] = {};
    for (int k0 = ky * 256; k0 < ky * 256 + 256; k0 += 32) {
        #pragma unroll
        for (int q = 0; q < 2; ++q) {
            int idx = q * 256 + tid;
            int kv = idx & 7, m = idx >> 3;
            float4 v = *(const float4*)(mean_feat + (size_t)m * E + k0 + kv * 4);
            As[kv * 4 + 0][m] = v.x;
            As[kv * 4 + 1][m] = v.y;
            As[kv * 4 + 2][m] = v.z;
            As[kv * 4 + 3][m] = v.w;
        }
        #pragma unroll
        for (int q = 0; q < 2; ++q) {
            int idx = q * 256 + tid;
            int n4 = idx & 15, kk = idx >> 4;
            float4 v = *(const float4*)(Wsrc + (size_t)(k0 + kk) * 256 + ncol0 + n4 * 4);
            *(float4*)&Bs[kk][n4 * 4] = v;
        }
        __syncthreads();
        #pragma unroll
        for (int kk = 0; kk < 32; ++kk) {
            float4 av = *(const float4*)&As[kk][ty * 4];
            float4 bv = *(const float4*)&Bs[kk][tx * 4];
            acc[0][0] += av.x * bv.x; acc[0][1] += av.x * bv.y; acc[0][2] += av.x * bv.z; acc[0][3] += av.x * bv.w;
            acc[1][0] += av.y * bv.x; acc[1][1] += av.y * bv.y; acc[1][2] += av.y * bv.z; acc[1][3] += av.y * bv.w;
            acc[2][0] += av.z * bv.x; acc[2][1] += av.z * bv.y; acc[2][2] += av.z * bv.z; acc[2][3] += av.z * bv.w;
            acc[3][0] += av.w * bv.x; acc[3][1] += av.w * bv.y; acc[3][2] += av.w * bv.z; acc[3][3] += av.w * bv.w;
        }
        __syncthreads();
    }
    #pragma unroll
    for (int a = 0; a < 4; ++a) {
        int row = ty * 4 + a;
        float4 o = {acc[a][0], acc[a][1], acc[a][2], acc[a][3]};
        *(float4*)(hpart + ((size_t)ky * B + row) * 512 + cb * 64 + tx * 4) = o;
    }
}

// ---------------- h0c0 reduce: sum partials, add bias, init h/c ----------------
__global__ __launch_bounds__(256) void h0c0_reduce(const float* __restrict__ hpart,
                                                   const float* __restrict__ b_hid,
                                                   const float* __restrict__ b_cell,
                                                   float* __restrict__ h,
                                                   float* __restrict__ c0,
                                                   float* __restrict__ xbuf) {
    int b = blockIdx.x, tid = threadIdx.x;
    float s0 = 0.f, s1 = 0.f;
    #pragma unroll
    for (int ky = 0; ky < 8; ++ky) {
        const float* hp = hpart + ((size_t)ky * B + b) * 512;
        s0 += hp[tid];
        s1 += hp[256 + tid];
    }
    float h0 = s0 + b_hid[tid];
    h[b * D + tid] = h0;
    c0[b * D + tid] = s1 + b_cell[tid];
    xbuf[(size_t)b * KX2 + 2048 + tid] = h0;
}

// ---------------- Gemb[t][b][n] = emb[tok[order[b],t]] @ W_ih[0:256]; grid (16, 31) ----------------
__global__ __launch_bounds__(256) void gemb_gemm(const float* __restrict__ emb,
                                                 const int* __restrict__ cap_tok,
                                                 const int* __restrict__ order,
                                                 const float* __restrict__ W_ih,
                                                 float* __restrict__ Gemb) {
    __shared__ float As[32][68];
    __shared__ float Bs[32][64];
    __shared__ int srcTok[64];
    int cb = blockIdx.x;   // 0..15
    int t  = blockIdx.y;   // 0..30
    int tid = threadIdx.x;
    if (tid < 64) srcTok[tid] = cap_tok[order[tid] * L + t];
    __syncthreads();
    int tx = tid & 15, ty = tid >> 4;
    float acc[4][4] = {};
    for (int k0 = 0; k0 < EM; k0 += 32) {
        #pragma unroll
        for (int q = 0; q < 2; ++q) {
            int idx = q * 256 + tid;
            int kv = idx & 7, m = idx >> 3;
            float4 v = *(const float4*)(emb + (size_t)srcTok[m] * EM + k0 + kv * 4);
            As[kv * 4 + 0][m] = v.x;
            As[kv * 4 + 1][m] = v.y;
            As[kv * 4 + 2][m] = v.z;
            As[kv * 4 + 3][m] = v.w;
        }
        #pragma unroll
        for (int q = 0; q < 2; ++q) {
            int idx = q * 256 + tid;
            int n4 = idx & 15, kk = idx >> 4;
            float4 v = *(const float4*)(W_ih + (size_t)(k0 + kk) * 1024 + cb * 64 + n4 * 4);
            *(float4*)&Bs[kk][n4 * 4] = v;
        }
        __syncthreads();
        #pragma unroll
        for (int kk = 0; kk < 32; ++kk) {
            float4 av = *(const float4*)&As[kk][ty * 4];
            float4 bv = *(const float4*)&Bs[kk][tx * 4];
            acc[0][0] += av.x * bv.x; acc[0][1] += av.x * bv.y; acc[0][2] += av.x * bv.z; acc[0][3] += av.x * bv.w;
            acc[1][0] += av.y * bv.x; acc[1][1] += av.y * bv.y; acc[1][2] += av.y * bv.z; acc[1][3] += av.y * bv.w;
            acc[2][0] += av.z * bv.x; acc[2][1] += av.z * bv.y; acc[2][2] += av.z * bv.z; acc[2][3] += av.z * bv.w;
            acc[3][0] += av.w * bv.x; acc[3][1] += av.w * bv.y; acc[3][2] += av.w * bv.z; acc[3][3] += av.w * bv.w;
        }
        __syncthreads();
    }
    #pragma unroll
    for (int a = 0; a < 4; ++a) {
        int row = ty * 4 + a;
        float4 o = {acc[a][0], acc[a][1], acc[a][2], acc[a][3]};
        *(float4*)(Gemb + ((size_t)t * B + row) * 1024 + cb * 64 + tx * 4) = o;
    }
}

// ---------------- fe partial GEMM: K split 4-way in one dispatch; grid (196, 4, 4) ----------------
__global__ __launch_bounds__(256) void fe_gemm(const float* __restrict__ feat,
                                               const int* __restrict__ order,
                                               const float* __restrict__ Wf,
                                               float* __restrict__ fepart) {
    __shared__ float As[32][68];
    __shared__ float Bs[32][64];
    __shared__ int srcRow[64];
    int rowBlock = blockIdx.x;   // 0..195
    int colBlock = blockIdx.y;   // 0..3
    int kz = blockIdx.z;         // 0..3
    int tid = threadIdx.x;
    if (tid < 64) {
        int gr = rowBlock * 64 + tid;
        int b = gr / P, p = gr % P;
        srcRow[tid] = order[b] * P + p;
    }
    __syncthreads();
    int tx = tid & 15, ty = tid >> 4;
    float acc[4][4] = {};
    for (int k0 = kz * 512; k0 < kz * 512 + 512; k0 += 32) {
        #pragma unroll
        for (int q = 0; q < 2; ++q) {
            int idx = q * 256 + tid;
            int kv = idx & 7, m = idx >> 3;
            float4 v = *(const float4*)(feat + (size_t)srcRow[m] * E + k0 + kv * 4);
            As[kv * 4 + 0][m] = v.x;
            As[kv * 4 + 1][m] = v.y;
            As[kv * 4 + 2][m] = v.z;
            As[kv * 4 + 3][m] = v.w;
        }
        {
            int n4 = tid & 15, kk = tid >> 4;   // kk 0..15
            float4 v = *(const float4*)(Wf + (size_t)(k0 + kk) * H_ + colBlock * 64 + n4 * 4);
            *(float4*)&Bs[kk][n4 * 4] = v;
            int kk2 = kk + 16;
            float4 v2 = *(const float4*)(Wf + (size_t)(k0 + kk2) * H_ + colBlock * 64 + n4 * 4);
            *(float4*)&Bs[kk2][n4 * 4] = v2;
        }
        __syncthreads();
        #pragma unroll
        for (int kk = 0; kk < 32; ++kk) {
            float4 av = *(const float4*)&As[kk][ty * 4];
            float4 bv = *(const float4*)&Bs[kk][tx * 4];
            acc[0][0] += av.x * bv.x; acc[0][1] += av.x * bv.y; acc[0][2] += av.x * bv.z; acc[0][3] += av.x * bv.w;
            acc[1][0] += av.y * bv.x; acc[1][1] += av.y * bv.y; acc[1][2] += av.y * bv.z; acc[1][3] += av.y * bv.w;
            acc[2][0] += av.z * bv.x; acc[2][1] += av.z * bv.y; acc[2][2] += av.z * bv.z; acc[2][3] += av.z * bv.w;
            acc[3][0] += av.w * bv.x; acc[3][1] += av.w * bv.y; acc[3][2] += av.w * bv.z; acc[3][3] += av.w * bv.w;
        }
        __syncthreads();
    }
    float* dst = fepart + (size_t)kz * FEPART_SZ;
    #pragma unroll
    for (int a = 0; a < 4; ++a) {
        int gr = rowBlock * 64 + ty * 4 + a;
        float4 o = {acc[a][0], acc[a][1], acc[a][2], acc[a][3]};
        *(float4*)(dst + (size_t)gr * H_ + colBlock * 64 + tx * 4) = o;
    }
}

// ---------------- fe reduce: fe = sum of 4 partials + bias ----------------
__global__ __launch_bounds__(256) void fe_reduce(float* __restrict__ fe,
                                                 const float* __restrict__ fepart,
                                                 const float* __restrict__ bf) {
    size_t f4 = (size_t)blockIdx.x * 256 + threadIdx.x;
    int col4 = (int)(f4 & 63);
    float4 a = *(const float4*)(fepart + f4 * 4);
    float4 b = *(const float4*)(fepart + FEPART_SZ + f4 * 4);
    float4 c = *(const float4*)(fepart + 2 * FEPART_SZ + f4 * 4);
    float4 d = *(const float4*)(fepart + 3 * FEPART_SZ + f4 * 4);
    float4 bias = *(const float4*)(bf + col4 * 4);
    float4 o = {a.x + b.x + c.x + d.x + bias.x,
                a.y + b.y + c.y + d.y + bias.y,
                a.z + b.z + c.z + d.z + bias.z,
                a.w + b.w + c.w + d.w + bias.w};
    *(float4*)(fe + f4 * 4) = o;
}

// ============ fused per-step kernel: pointwise + attention + ctx, grid (B,8) ============
__global__ __launch_bounds__(256) void attn_ctx(const int* __restrict__ target,
                                                const float* __restrict__ gpart,
                                                const float* __restrict__ Gemb,
                                                const float* __restrict__ b_ih,
                                                const float* __restrict__ b_hh,
                                                const int* __restrict__ order,
                                                const float* __restrict__ Wh,
                                                const float* __restrict__ bh,
                                                const float* __restrict__ We,
                                                const float* __restrict__ be,
                                                const float* __restrict__ fe,
                                                const float* __restrict__ h0,
                                                const float* __restrict__ c_rd,
                                                float* __restrict__ c_wr,
                                                float* __restrict__ hn_all,
                                                float* __restrict__ xbuf,
                                                float* __restrict__ out2,
                                                const float* __restrict__ feat,
                                                const float* __restrict__ W_gate,
                                                const float* __restrict__ b_gate,
                                                int t) {
    int b = blockIdx.x, y = blockIdx.y, tid = threadIdx.x;
    int tgt = target[b];
    bool pw_active = (t > 0) && (tgt > t - 1);
    bool at_active = (tgt > t);
    if (!at_active && !(pw_active && y == 0)) return;

    __shared__ float hs[D];
    __shared__ float hes[D];
    __shared__ float es[200];
    __shared__ float red[4];
    __shared__ float4 rc[3][64];
    __shared__ float4 rg[3][64];

    if (pw_active) {
        int d = tid;
        const float* ge = Gemb + ((size_t)(t - 1) * B + b) * 1024;
        float gi = b_ih[d] + b_hh[d] + ge[d];
        float gf = b_ih[D + d] + b_hh[D + d] + ge[D + d];
        float gg = b_ih[2 * D + d] + b_hh[2 * D + d] + ge[2 * D + d];
        float go = b_ih[3 * D + d] + b_hh[3 * D + d] + ge[3 * D + d];
        #pragma unroll
        for (int ky = 0; ky < NKY; ++ky) {
            const float* gp = gpart + ((size_t)ky * B + b) * 1024;
            gi += gp[d];
            gf += gp[D + d];
            gg += gp[2 * D + d];
            go += gp[3 * D + d];
        }
        float c_old = c_rd[b * D + d];
        float si = 1.f / (1.f + expf(-gi));
        float sf = 1.f / (1.f + expf(-gf));
        float so = 1.f / (1.f + expf(-go));
        float cn = sf * c_old + si * tanhf(gg);
        float hnv = so * tanhf(cn);
        hs[d] = hnv;
        if (y == 0) {
            c_wr[b * D + d] = cn;
            hn_all[((size_t)(t - 1) * B + b) * D + d] = hnv;
            xbuf[(size_t)b * KX2 + 2048 + d] = hnv;
        }
    } else {
        hs[tid] = h0[b * D + tid];   // only at t == 0
    }
    __syncthreads();
    if (!at_active) return;

    // ---- he = hs @ Wh + bh : float4 col-quads, 4-way K-split across thread groups ----
    {
        int cq = tid & 63;        // col-quad index: cols 4cq..4cq+3
        int kq = tid >> 6;        // 0..3 -> K slice [kq*64, kq*64+64)
        float4 a = {0.f, 0.f, 0.f, 0.f};
        const float4* w4 = (const float4*)Wh + cq;    // Wh[k][4cq..] at w4[k*64]
        #pragma unroll 4
        for (int k = kq * 64; k < kq * 64 + 64; ++k) {
            float hv = hs[k];
            float4 wv = w4[(size_t)k * 64];
            a.x += hv * wv.x; a.y += hv * wv.y; a.z += hv * wv.z; a.w += hv * wv.w;
        }
        if (kq) rc[kq - 1][cq] = a;
        __syncthreads();
        if (kq == 0) {
            #pragma unroll
            for (int j = 0; j < 3; ++j) {
                float4 r = rc[j][cq];
                a.x += r.x; a.y += r.y; a.z += r.z; a.w += r.w;
            }
            float4 bhv = *(const float4*)(bh + cq * 4);
            float4 o = {a.x + bhv.x, a.y + bhv.y, a.z + bhv.z, a.w + bhv.w};
            *(float4*)&hes[cq * 4] = o;
        }
        __syncthreads();
    }

    int wave = tid >> 6, lane = tid & 63;
    {
        float4 he4 = *(const float4*)&hes[lane * 4];
        float4 we4 = *(const float4*)(We + lane * 4);
        for (int p = wave; p < P; p += 4) {
            float4 fv = *(const float4*)(fe + ((size_t)b * P + p) * H_ + lane * 4);
            float x0 = fv.x + he4.x; x0 = x0 > 0.f ? x0 : 0.f;
            float x1 = fv.y + he4.y; x1 = x1 > 0.f ? x1 : 0.f;
            float x2 = fv.z + he4.z; x2 = x2 > 0.f ? x2 : 0.f;
            float x3 = fv.w + he4.w; x3 = x3 > 0.f ? x3 : 0.f;
            float s = x0 * we4.x + x1 * we4.y + x2 * we4.z + x3 * we4.w;
            #pragma unroll
            for (int off = 32; off > 0; off >>= 1) s += __shfl_down(s, off);
            if (lane == 0) es[p] = s + be[0];
        }
    }
    __syncthreads();
    {
        float mx = -1e30f;
        for (int p = tid; p < P; p += 256) mx = fmaxf(mx, es[p]);
        #pragma unroll
        for (int off = 32; off > 0; off >>= 1) mx = fmaxf(mx, __shfl_down(mx, off));
        if (lane == 0) red[wave] = mx;
        __syncthreads();
        mx = fmaxf(fmaxf(red[0], red[1]), fmaxf(red[2], red[3]));
        __syncthreads();
        float sum = 0.f;
        for (int p = tid; p < P; p += 256) {
            float ex = expf(es[p] - mx);
            es[p] = ex;
            sum += ex;
        }
        #pragma unroll
        for (int off = 32; off > 0; off >>= 1) sum += __shfl_down(sum, off);
        if (lane == 0) red[wave] = sum;
        __syncthreads();
        sum = red[0] + red[1] + red[2] + red[3];
        float inv = 1.0f / sum;
        for (int p = tid; p < P; p += 256) {
            float wv = es[p] * inv;
            es[p] = wv;
            if (y == 0) out2[((size_t)b * T + t) * P + p] = wv;
        }
    }
    __syncthreads();

    {
        int c4 = tid & 63, q = tid >> 6;
        int src = order[b];
        const float4* f4 = (const float4*)(feat + (size_t)src * P * E) + y * 64 + c4;
        float4 acc = {0.f, 0.f, 0.f, 0.f};
        for (int p = q * 49; p < q * 49 + 49; ++p) {
            float w = es[p];
            float4 fv = f4[(size_t)p * 512];
            acc.x += w * fv.x; acc.y += w * fv.y; acc.z += w * fv.z; acc.w += w * fv.w;
        }
        const float4* g4 = (const float4*)W_gate + y * 64 + c4;
        float4 gacc = {0.f, 0.f, 0.f, 0.f};
        for (int k = q * 64; k < q * 64 + 64; ++k) {
            float hv = hs[k];
            float4 wv = g4[(size_t)k * 512];
            gacc.x += hv * wv.x; gacc.y += hv * wv.y; gacc.z += hv * wv.z; gacc.w += hv * wv.w;
        }
        if (q) { rc[q - 1][c4] = acc; rg[q - 1][c4] = gacc; }
        __syncthreads();
        if (q == 0) {
            #pragma unroll
            for (int j = 0; j < 3; ++j) {
                float4 a = rc[j][c4], g = rg[j][c4];
                acc.x += a.x; acc.y += a.y; acc.z += a.z; acc.w += a.w;
                gacc.x += g.x; gacc.y += g.y; gacc.z += g.z; gacc.w += g.w;
            }
            float4 gb = *(const float4*)(b_gate + (y * 64 + c4) * 4);
            float4 o;
            o.x = acc.x / (1.f + expf(-(gacc.x + gb.x)));
            o.y = acc.y / (1.f + expf(-(gacc.y + gb.y)));
            o.z = acc.z / (1.f + expf(-(gacc.z + gb.z)));
            o.w = acc.w / (1.f + expf(-(gacc.w + gb.w)));
            *(float4*)(xbuf + (size_t)b * KX2 + (y * 64 + c4) * 4) = o;
        }
    }
}

// ---------------- final pointwise only (t == T) ----------------
__global__ __launch_bounds__(256) void pw_final(const int* __restrict__ target,
                                                const float* __restrict__ gpart,
                                                const float* __restrict__ Gemb,
                                                const float* __restrict__ b_ih,
                                                const float* __restrict__ b_hh,
                                                const float* __restrict__ c_rd,
                                                float* __restrict__ hn_all) {
    int b = blockIdx.x;
    if (target[b] < T) return;
    int d = threadIdx.x;
    const float* ge = Gemb + ((size_t)(T - 1) * B + b) * 1024;
    float gi = b_ih[d] + b_hh[d] + ge[d];
    float gf = b_ih[D + d] + b_hh[D + d] + ge[D + d];
    float gg = b_ih[2 * D + d] + b_hh[2 * D + d] + ge[2 * D + d];
    float go = b_ih[3 * D + d] + b_hh[3 * D + d] + ge[3 * D + d];
    #pragma unroll
    for (int ky = 0; ky < NKY; ++ky) {
        const float* gp = gpart + ((size_t)ky * B + b) * 1024;
        gi += gp[d];
        gf += gp[D + d];
        gg += gp[2 * D + d];
        go += gp[3 * D + d];
    }
    float c_old = c_rd[b * D + d];
    float si = 1.f / (1.f + expf(-gi));
    float sf = 1.f / (1.f + expf(-gf));
    float so = 1.f / (1.f + expf(-go));
    float cn = sf * c_old + si * tanhf(gg);
    float hnv = so * tanhf(cn);
    hn_all[((size_t)(T - 1) * B + b) * D + d] = hnv;
}

// ---------------- gate GEMM: K = 2304 split 18-way; grid (16, 18) ----------------
__global__ __launch_bounds__(256) void lstm_gemm(const float* __restrict__ xbuf,
                                                 const float* __restrict__ W_ih,
                                                 const float* __restrict__ W_hh,
                                                 float* __restrict__ gpart) {
    __shared__ float As[32][68];
    __shared__ float Bs[32][64];
    int cb = blockIdx.x;   // 0..15
    int ky = blockIdx.y;   // 0..17
    int tid = threadIdx.x;
    int tx = tid & 15, ty = tid >> 4;
    float acc[4][4] = {};
    int k0base = ky * 128;
    for (int k0 = k0base; k0 < k0base + 128; k0 += 32) {
        #pragma unroll
        for (int q = 0; q < 2; ++q) {
            int idx = q * 256 + tid;
            int kv = idx & 7, m = idx >> 3;
            float4 v = *(const float4*)(xbuf + (size_t)m * KX2 + k0 + kv * 4);
            As[kv * 4 + 0][m] = v.x;
            As[kv * 4 + 1][m] = v.y;
            As[kv * 4 + 2][m] = v.z;
            As[kv * 4 + 3][m] = v.w;
        }
        #pragma unroll
        for (int q = 0; q < 2; ++q) {
            int idx = q * 256 + tid;
            int n4 = idx & 15, kk = idx >> 4;
            int k = k0 + kk;
            const float* src = (k < E) ? (W_ih + (size_t)(EM + k) * 1024)
                                       : (W_hh + (size_t)(k - E) * 1024);
            float4 v = *(const float4*)(src + cb * 64 + n4 * 4);
            *(float4*)&Bs[kk][n4 * 4] = v;
        }
        __syncthreads();
        #pragma unroll
        for (int kk = 0; kk < 32; ++kk) {
            float4 av = *(const float4*)&As[kk][ty * 4];
            float4 bv = *(const float4*)&Bs[kk][tx * 4];
            acc[0][0] += av.x * bv.x; acc[0][1] += av.x * bv.y; acc[0][2] += av.x * bv.z; acc[0][3] += av.x * bv.w;
            acc[1][0] += av.y * bv.x; acc[1][1] += av.y * bv.y; acc[1][2] += av.y * bv.z; acc[1][3] += av.y * bv.w;
            acc[2][0] += av.z * bv.x; acc[2][1] += av.z * bv.y; acc[2][2] += av.z * bv.z; acc[2][3] += av.z * bv.w;
            acc[3][0] += av.w * bv.x; acc[3][1] += av.w * bv.y; acc[3][2] += av.w * bv.z; acc[3][3] += av.w * bv.w;
        }
        __syncthreads();
    }
    #pragma unroll
    for (int a = 0; a < 4; ++a) {
        int bidx = ty * 4 + a;
        float4 o = {acc[a][0], acc[a][1], acc[a][2], acc[a][3]};
        *(float4*)(gpart + ((size_t)ky * B + bidx) * 1024 + cb * 64 + tx * 4) = o;
    }
}

// ---------------- batched head: grid (157, 62); writes zeros for masked entries ----------------
__global__ __launch_bounds__(256) void head_batch(const float* __restrict__ hn_all,
                                                  const float* __restrict__ W_head,
                                                  const float* __restrict__ b_head,
                                                  const int* __restrict__ target,
                                                  float* __restrict__ out1) {
    int by = blockIdx.y;
    int t = by >> 1, qh = by & 1;
    int cb = blockIdx.x;
    int tid = threadIdx.x;
    int col = cb * 64 + (tid & 63);
    int rgrp = (tid >> 6) * 8;
    if (target[qh * 32] <= t) {          // whole 32-row tile masked: write zeros
        if (col < V) {
            #pragma unroll
            for (int r = 0; r < 8; ++r) {
                int brow = qh * 32 + rgrp + r;
                out1[((size_t)brow * T + t) * V + col] = 0.f;
            }
        }
        return;
    }
    __shared__ float hs[32][260];
    #pragma unroll
    for (int q = 0; q < 8; ++q) {
        int idx = q * 256 + tid;
        int r = idx >> 6, kq = idx & 63;
        float4 v = *(const float4*)(hn_all + ((size_t)t * B + qh * 32 + r) * D + kq * 4);
        *(float4*)&hs[r][kq * 4] = v;
    }
    __syncthreads();
    if (col < V) {
        float acc[8] = {};
        for (int kq = 0; kq < 64; ++kq) {
            float w0 = W_head[(size_t)(kq * 4 + 0) * V + col];
            float w1 = W_head[(size_t)(kq * 4 + 1) * V + col];
            float w2 = W_head[(size_t)(kq * 4 + 2) * V + col];
            float w3 = W_head[(size_t)(kq * 4 + 3) * V + col];
            #pragma unroll
            for (int r = 0; r < 8; ++r) {
                float4 hv = *(const float4*)&hs[rgrp + r][kq * 4];
                acc[r] += hv.x * w0 + hv.y * w1 + hv.z * w2 + hv.w * w3;
            }
        }
        float bh_ = b_head[col];
        #pragma unroll
        for (int r = 0; r < 8; ++r) {
            int brow = qh * 32 + rgrp + r;
            out1[((size_t)brow * T + t) * V + col] =
                (target[brow] > t) ? (acc[r] + bh_) : 0.f;
        }
    }
}

extern "C" void kernel_launch(void* const* d_in, const int* in_sizes, int n_in,
                              void* d_out, int out_size, void* d_ws, size_t ws_size,
                              hipStream_t stream) {
    const float* feat   = (const float*)d_in[0];
    const int*   tok    = (const int*)d_in[1];
    const int*   clen   = (const int*)d_in[2];
    const float* Wf     = (const float*)d_in[3];
    const float* bf     = (const float*)d_in[4];
    const float* Wh     = (const float*)d_in[5];
    const float* bh     = (const float*)d_in[6];
    const float* We     = (const float*)d_in[7];
    const float* be     = (const float*)d_in[8];
    const float* emb    = (const float*)d_in[9];
    const float* W_ih   = (const float*)d_in[10];
    const float* b_ih   = (const float*)d_in[11];
    const float* W_hh   = (const float*)d_in[12];
    const float* b_hh   = (const float*)d_in[13];
    const float* W_hid  = (const float*)d_in[14];
    const float* b_hid  = (const float*)d_in[15];
    const float* W_cell = (const float*)d_in[16];
    const float* b_cell = (const float*)d_in[17];
    const float* W_gate = (const float*)d_in[18];
    const float* b_gate = (const float*)d_in[19];
    const float* W_head = (const float*)d_in[20];
    const float* b_head = (const float*)d_in[21];

    float* out1 = (float*)d_out;                       // B*T*V floats (19.84M)
    float* out2 = out1 + (size_t)B * T * V;            // B*T*P floats

    // ---- workspace (~17 MB) ----
    char* wp = (char*)d_ws;
    int* order   = (int*)wp;           wp += 256;
    int* targetp = (int*)wp;           wp += 256;
    float* fe    = (float*)wp;         wp += (size_t)B * P * H_ * sizeof(float);
    float* hbuf  = (float*)wp;         wp += (size_t)B * D * sizeof(float);
    float* cbuf  = (float*)wp;         wp += (size_t)2 * B * D * sizeof(float);
    float* xbuf  = (float*)wp;         wp += (size_t)B * KX2 * sizeof(float);
    float* mean_feat = (float*)wp;     wp += (size_t)B * E * sizeof(float);
    float* hpart = (float*)wp;         wp += (size_t)8 * B * 512 * sizeof(float);
    float* hn_all = (float*)wp;        wp += (size_t)T * B * D * sizeof(float);

    // ---- transient scratch inside out1 (fully overwritten by head_batch at the end) ----
    float* fepart = out1;                               // 4 * FEPART_SZ = 12.85M floats
    float* Gemb   = out1 + 4 * FEPART_SZ;               // T*B*1024 = 2.03M floats
    float* gpart  = Gemb + (size_t)T * B * 1024;        // NKY*B*1024 = 1.18M (total 16.06M < 19.84M)

    hipMemsetAsync(out2, 0, (size_t)B * T * P * sizeof(float), stream);

    sort_kernel<<<1, 64, 0, stream>>>(clen, order, targetp);
    mean_kernel<<<dim3(B, E / 256), 256, 0, stream>>>(feat, order, mean_feat);
    h0c0_gemm<<<dim3(8, 8), 256, 0, stream>>>(mean_feat, W_hid, W_cell, hpart);
    h0c0_reduce<<<B, 256, 0, stream>>>(hpart, b_hid, b_cell, hbuf, cbuf, xbuf);
    fe_gemm<<<dim3(196, 4, 4), 256, 0, stream>>>(feat, order, Wf, fepart);
    fe_reduce<<<3136, 256, 0, stream>>>(fe, fepart, bf);
    gemb_gemm<<<dim3(16, T), 256, 0, stream>>>(emb, tok, order, W_ih, Gemb);

    for (int t = 0; t < T; ++t) {
        attn_ctx<<<dim3(B, 8), 256, 0, stream>>>(targetp, gpart, Gemb, b_ih, b_hh,
                                                 order, Wh, bh, We, be, fe, hbuf,
                                                 cbuf + (size_t)((t + 1) & 1) * B * D,
                                                 cbuf + (size_t)(t & 1) * B * D,
                                                 hn_all, xbuf, out2,
                                                 feat, W_gate, b_gate, t);
        lstm_gemm<<<dim3(16, NKY), 256, 0, stream>>>(xbuf, W_ih, W_hh, gpart);
    }
    pw_final<<<B, 256, 0, stream>>>(targetp, gpart, Gemb, b_ih, b_hh, cbuf, hn_all);

    // head writes every (b,t,col) exactly once (zeros for masked) -> no out1 memset needed
    head_batch<<<dim3(157, 62), 256, 0, stream>>>(hn_all, W_head, b_head, targetp, out1);
}

// Round 7
// 2353.614 us; speedup vs baseline: 4.5087x; 1.0327x over previous
//
#include <hip/hip_runtime.h>
#include <math.h>

#define B 64
#define P 196
#define E 2048
#define D 256
#define H_ 256
#define EM 256
#define V 10000
#define L 32
#define T 31
#define KX2 2304   // E + D  (ctx | h) -- emb contribution precomputed in Gemb
#define NKY 18     // lstm split-K factor: 2304 = 18 * 128
#define FEPART_SZ ((size_t)B * P * H_)   // 3,211,264 floats per fe partial

// ---------------- sort: stable argsort descending by length ----------------
__global__ __launch_bounds__(64) void sort_kernel(const int* __restrict__ clen,
                                                  int* __restrict__ order,
                                                  int* __restrict__ target) {
    __shared__ int len_s[B];
    int i = threadIdx.x;
    len_s[i] = clen[i];
    __syncthreads();
    int li = len_s[i];
    int rank = 0;
    for (int j = 0; j < B; ++j) {
        int lj = len_s[j];
        if (lj > li || (lj == li && j < i)) rank++;
    }
    order[rank] = i;
    target[rank] = li - 1;
}

// ---------------- mean_feat[b][e] = mean_p feat[src][p][e] ----------------
__global__ __launch_bounds__(256) void mean_kernel(const float* __restrict__ feat,
                                                   const int* __restrict__ order,
                                                   float* __restrict__ mean_feat) {
    int b = blockIdx.x;
    int e = blockIdx.y * 256 + threadIdx.x;
    int src = order[b];
    const float* fp = feat + (size_t)src * P * E + e;
    float acc = 0.f;
    #pragma unroll 4
    for (int p = 0; p < P; ++p) acc += fp[(size_t)p * E];
    mean_feat[b * E + e] = acc * (1.0f / (float)P);
}

// ---------------- h0c0 as split-K GEMM: hpart[ky][64][512] ----------------
__global__ __launch_bounds__(256) void h0c0_gemm(const float* __restrict__ mean_feat,
                                                 const float* __restrict__ W_hid,
                                                 const float* __restrict__ W_cell,
                                                 float* __restrict__ hpart) {
    __shared__ float As[32][68];
    __shared__ float Bs[32][64];
    int cb = blockIdx.x;   // 0..7
    int ky = blockIdx.y;   // 0..7
    int tid = threadIdx.x;
    int tx = tid & 15, ty = tid >> 4;
    const float* Wsrc;
    int ncol0;
    if (cb < 4) { Wsrc = W_hid;  ncol0 = cb * 64; }
    else        { Wsrc = W_cell; ncol0 = (cb - 4) * 64; }
    float acc[4][4] = {};
    for (int k0 = ky * 256; k0 < ky * 256 + 256; k0 += 32) {
        #pragma unroll
        for (int q = 0; q < 2; ++q) {
            int idx = q * 256 + tid;
            int kv = idx & 7, m = idx >> 3;
            float4 v = *(const float4*)(mean_feat + (size_t)m * E + k0 + kv * 4);
            As[kv * 4 + 0][m] = v.x;
            As[kv * 4 + 1][m] = v.y;
            As[kv * 4 + 2][m] = v.z;
            As[kv * 4 + 3][m] = v.w;
        }
        #pragma unroll
        for (int q = 0; q < 2; ++q) {
            int idx = q * 256 + tid;
            int n4 = idx & 15, kk = idx >> 4;
            float4 v = *(const float4*)(Wsrc + (size_t)(k0 + kk) * 256 + ncol0 + n4 * 4);
            *(float4*)&Bs[kk][n4 * 4] = v;
        }
        __syncthreads();
        #pragma unroll
        for (int kk = 0; kk < 32; ++kk) {
            float4 av = *(const float4*)&As[kk][ty * 4];
            float4 bv = *(const float4*)&Bs[kk][tx * 4];
            acc[0][0] += av.x * bv.x; acc[0][1] += av.x * bv.y; acc[0][2] += av.x * bv.z; acc[0][3] += av.x * bv.w;
            acc[1][0] += av.y * bv.x; acc[1][1] += av.y * bv.y; acc[1][2] += av.y * bv.z; acc[1][3] += av.y * bv.w;
            acc[2][0] += av.z * bv.x; acc[2][1] += av.z * bv.y; acc[2][2] += av.z * bv.z; acc[2][3] += av.z * bv.w;
            acc[3][0] += av.w * bv.x; acc[3][1] += av.w * bv.y; acc[3][2] += av.w * bv.z; acc[3][3] += av.w * bv.w;
        }
        __syncthreads();
    }
    #pragma unroll
    for (int a = 0; a < 4; ++a) {
        int row = ty * 4 + a;
        float4 o = {acc[a][0], acc[a][1], acc[a][2], acc[a][3]};
        *(float4*)(hpart + ((size_t)ky * B + row) * 512 + cb * 64 + tx * 4) = o;
    }
}

// ---------------- h0c0 reduce: sum partials, add bias, init h/c ----------------
__global__ __launch_bounds__(256) void h0c0_reduce(const float* __restrict__ hpart,
                                                   const float* __restrict__ b_hid,
                                                   const float* __restrict__ b_cell,
                                                   float* __restrict__ h,
                                                   float* __restrict__ c0,
                                                   float* __restrict__ xbuf) {
    int b = blockIdx.x, tid = threadIdx.x;
    float s0 = 0.f, s1 = 0.f;
    #pragma unroll
    for (int ky = 0; ky < 8; ++ky) {
        const float* hp = hpart + ((size_t)ky * B + b) * 512;
        s0 += hp[tid];
        s1 += hp[256 + tid];
    }
    float h0 = s0 + b_hid[tid];
    h[b * D + tid] = h0;
    c0[b * D + tid] = s1 + b_cell[tid];
    xbuf[(size_t)b * KX2 + 2048 + tid] = h0;
}

// ---------------- Gemb[t][b][n] = emb[tok[order[b],t]] @ W_ih[0:256]; grid (16, 31) ----------------
__global__ __launch_bounds__(256) void gemb_gemm(const float* __restrict__ emb,
                                                 const int* __restrict__ cap_tok,
                                                 const int* __restrict__ order,
                                                 const float* __restrict__ W_ih,
                                                 float* __restrict__ Gemb) {
    __shared__ float As[32][68];
    __shared__ float Bs[32][64];
    __shared__ int srcTok[64];
    int cb = blockIdx.x;   // 0..15
    int t  = blockIdx.y;   // 0..30
    int tid = threadIdx.x;
    if (tid < 64) srcTok[tid] = cap_tok[order[tid] * L + t];
    __syncthreads();
    int tx = tid & 15, ty = tid >> 4;
    float acc[4][4] = {};
    for (int k0 = 0; k0 < EM; k0 += 32) {
        #pragma unroll
        for (int q = 0; q < 2; ++q) {
            int idx = q * 256 + tid;
            int kv = idx & 7, m = idx >> 3;
            float4 v = *(const float4*)(emb + (size_t)srcTok[m] * EM + k0 + kv * 4);
            As[kv * 4 + 0][m] = v.x;
            As[kv * 4 + 1][m] = v.y;
            As[kv * 4 + 2][m] = v.z;
            As[kv * 4 + 3][m] = v.w;
        }
        #pragma unroll
        for (int q = 0; q < 2; ++q) {
            int idx = q * 256 + tid;
            int n4 = idx & 15, kk = idx >> 4;
            float4 v = *(const float4*)(W_ih + (size_t)(k0 + kk) * 1024 + cb * 64 + n4 * 4);
            *(float4*)&Bs[kk][n4 * 4] = v;
        }
        __syncthreads();
        #pragma unroll
        for (int kk = 0; kk < 32; ++kk) {
            float4 av = *(const float4*)&As[kk][ty * 4];
            float4 bv = *(const float4*)&Bs[kk][tx * 4];
            acc[0][0] += av.x * bv.x; acc[0][1] += av.x * bv.y; acc[0][2] += av.x * bv.z; acc[0][3] += av.x * bv.w;
            acc[1][0] += av.y * bv.x; acc[1][1] += av.y * bv.y; acc[1][2] += av.y * bv.z; acc[1][3] += av.y * bv.w;
            acc[2][0] += av.z * bv.x; acc[2][1] += av.z * bv.y; acc[2][2] += av.z * bv.z; acc[2][3] += av.z * bv.w;
            acc[3][0] += av.w * bv.x; acc[3][1] += av.w * bv.y; acc[3][2] += av.w * bv.z; acc[3][3] += av.w * bv.w;
        }
        __syncthreads();
    }
    #pragma unroll
    for (int a = 0; a < 4; ++a) {
        int row = ty * 4 + a;
        float4 o = {acc[a][0], acc[a][1], acc[a][2], acc[a][3]};
        *(float4*)(Gemb + ((size_t)t * B + row) * 1024 + cb * 64 + tx * 4) = o;
    }
}

// ---------------- fe partial GEMM: K split 4-way in one dispatch; grid (196, 4, 4) ----------------
__global__ __launch_bounds__(256) void fe_gemm(const float* __restrict__ feat,
                                               const int* __restrict__ order,
                                               const float* __restrict__ Wf,
                                               float* __restrict__ fepart) {
    __shared__ float As[32][68];
    __shared__ float Bs[32][64];
    __shared__ int srcRow[64];
    int rowBlock = blockIdx.x;   // 0..195
    int colBlock = blockIdx.y;   // 0..3
    int kz = blockIdx.z;         // 0..3
    int tid = threadIdx.x;
    if (tid < 64) {
        int gr = rowBlock * 64 + tid;
        int b = gr / P, p = gr % P;
        srcRow[tid] = order[b] * P + p;
    }
    __syncthreads();
    int tx = tid & 15, ty = tid >> 4;
    float acc[4][4] = {};
    for (int k0 = kz * 512; k0 < kz * 512 + 512; k0 += 32) {
        #pragma unroll
        for (int q = 0; q < 2; ++q) {
            int idx = q * 256 + tid;
            int kv = idx & 7, m = idx >> 3;
            float4 v = *(const float4*)(feat + (size_t)srcRow[m] * E + k0 + kv * 4);
            As[kv * 4 + 0][m] = v.x;
            As[kv * 4 + 1][m] = v.y;
            As[kv * 4 + 2][m] = v.z;
            As[kv * 4 + 3][m] = v.w;
        }
        {
            int n4 = tid & 15, kk = tid >> 4;   // kk 0..15
            float4 v = *(const float4*)(Wf + (size_t)(k0 + kk) * H_ + colBlock * 64 + n4 * 4);
            *(float4*)&Bs[kk][n4 * 4] = v;
            int kk2 = kk + 16;
            float4 v2 = *(const float4*)(Wf + (size_t)(k0 + kk2) * H_ + colBlock * 64 + n4 * 4);
            *(float4*)&Bs[kk2][n4 * 4] = v2;
        }
        __syncthreads();
        #pragma unroll
        for (int kk = 0; kk < 32; ++kk) {
            float4 av = *(const float4*)&As[kk][ty * 4];
            float4 bv = *(const float4*)&Bs[kk][tx * 4];
            acc[0][0] += av.x * bv.x; acc[0][1] += av.x * bv.y; acc[0][2] += av.x * bv.z; acc[0][3] += av.x * bv.w;
            acc[1][0] += av.y * bv.x; acc[1][1] += av.y * bv.y; acc[1][2] += av.y * bv.z; acc[1][3] += av.y * bv.w;
            acc[2][0] += av.z * bv.x; acc[2][1] += av.z * bv.y; acc[2][2] += av.z * bv.z; acc[2][3] += av.z * bv.w;
            acc[3][0] += av.w * bv.x; acc[3][1] += av.w * bv.y; acc[3][2] += av.w * bv.z; acc[3][3] += av.w * bv.w;
        }
        __syncthreads();
    }
    float* dst = fepart + (size_t)kz * FEPART_SZ;
    #pragma unroll
    for (int a = 0; a < 4; ++a) {
        int gr = rowBlock * 64 + ty * 4 + a;
        float4 o = {acc[a][0], acc[a][1], acc[a][2], acc[a][3]};
        *(float4*)(dst + (size_t)gr * H_ + colBlock * 64 + tx * 4) = o;
    }
}

// ---------------- fe reduce: fe = sum of 4 partials + bias ----------------
__global__ __launch_bounds__(256) void fe_reduce(float* __restrict__ fe,
                                                 const float* __restrict__ fepart,
                                                 const float* __restrict__ bf) {
    size_t f4 = (size_t)blockIdx.x * 256 + threadIdx.x;
    int col4 = (int)(f4 & 63);
    float4 a = *(const float4*)(fepart + f4 * 4);
    float4 b = *(const float4*)(fepart + FEPART_SZ + f4 * 4);
    float4 c = *(const float4*)(fepart + 2 * FEPART_SZ + f4 * 4);
    float4 d = *(const float4*)(fepart + 3 * FEPART_SZ + f4 * 4);
    float4 bias = *(const float4*)(bf + col4 * 4);
    float4 o = {a.x + b.x + c.x + d.x + bias.x,
                a.y + b.y + c.y + d.y + bias.y,
                a.z + b.z + c.z + d.z + bias.z,
                a.w + b.w + c.w + d.w + bias.w};
    *(float4*)(fe + f4 * 4) = o;
}

// ============ fused per-step kernel: pointwise + attention + ctx, grid (B,8) ============
__global__ __launch_bounds__(256) void attn_ctx(const int* __restrict__ target,
                                                const float* __restrict__ gpart,
                                                const float* __restrict__ Gemb,
                                                const float* __restrict__ b_ih,
                                                const float* __restrict__ b_hh,
                                                const int* __restrict__ order,
                                                const float* __restrict__ Wh,
                                                const float* __restrict__ bh,
                                                const float* __restrict__ We,
                                                const float* __restrict__ be,
                                                const float* __restrict__ fe,
                                                const float* __restrict__ h0,
                                                const float* __restrict__ c_rd,
                                                float* __restrict__ c_wr,
                                                float* __restrict__ hn_all,
                                                float* __restrict__ xbuf,
                                                float* __restrict__ out2,
                                                const float* __restrict__ feat,
                                                const float* __restrict__ W_gate,
                                                const float* __restrict__ b_gate,
                                                int t) {
    int b = blockIdx.x, y = blockIdx.y, tid = threadIdx.x;
    int tgt = target[b];
    bool pw_active = (t > 0) && (tgt > t - 1);
    bool at_active = (tgt > t);
    if (!at_active && !(pw_active && y == 0)) return;

    __shared__ float hs[D];
    __shared__ float hes[D];
    __shared__ float es[200];
    __shared__ float red[4];
    __shared__ float4 rc[3][64];
    __shared__ float4 rg[3][64];

    if (pw_active) {
        int d = tid;
        const float* ge = Gemb + ((size_t)(t - 1) * B + b) * 1024;
        float gi = b_ih[d] + b_hh[d] + ge[d];
        float gf = b_ih[D + d] + b_hh[D + d] + ge[D + d];
        float gg = b_ih[2 * D + d] + b_hh[2 * D + d] + ge[2 * D + d];
        float go = b_ih[3 * D + d] + b_hh[3 * D + d] + ge[3 * D + d];
        #pragma unroll
        for (int ky = 0; ky < NKY; ++ky) {
            const float* gp = gpart + ((size_t)ky * B + b) * 1024;
            gi += gp[d];
            gf += gp[D + d];
            gg += gp[2 * D + d];
            go += gp[3 * D + d];
        }
        float c_old = c_rd[b * D + d];
        float si = 1.f / (1.f + expf(-gi));
        float sf = 1.f / (1.f + expf(-gf));
        float so = 1.f / (1.f + expf(-go));
        float cn = sf * c_old + si * tanhf(gg);
        float hnv = so * tanhf(cn);
        hs[d] = hnv;
        if (y == 0) {
            c_wr[b * D + d] = cn;
            hn_all[((size_t)(t - 1) * B + b) * D + d] = hnv;
            xbuf[(size_t)b * KX2 + 2048 + d] = hnv;
        }
    } else {
        hs[tid] = h0[b * D + tid];   // only at t == 0
    }
    __syncthreads();
    if (!at_active) return;

    // ---- he = hs @ Wh + bh : float4 col-quads, 4-way K-split across thread groups ----
    {
        int cq = tid & 63;        // col-quad index: cols 4cq..4cq+3
        int kq = tid >> 6;        // 0..3 -> K slice [kq*64, kq*64+64)
        float4 a = {0.f, 0.f, 0.f, 0.f};
        const float4* w4 = (const float4*)Wh + cq;    // Wh[k][4cq..] at w4[k*64]
        #pragma unroll 4
        for (int k = kq * 64; k < kq * 64 + 64; ++k) {
            float hv = hs[k];
            float4 wv = w4[(size_t)k * 64];
            a.x += hv * wv.x; a.y += hv * wv.y; a.z += hv * wv.z; a.w += hv * wv.w;
        }
        if (kq) rc[kq - 1][cq] = a;
        __syncthreads();
        if (kq == 0) {
            #pragma unroll
            for (int j = 0; j < 3; ++j) {
                float4 r = rc[j][cq];
                a.x += r.x; a.y += r.y; a.z += r.z; a.w += r.w;
            }
            float4 bhv = *(const float4*)(bh + cq * 4);
            float4 o = {a.x + bhv.x, a.y + bhv.y, a.z + bhv.z, a.w + bhv.w};
            *(float4*)&hes[cq * 4] = o;
        }
        __syncthreads();
    }

    int wave = tid >> 6, lane = tid & 63;
    {
        float4 he4 = *(const float4*)&hes[lane * 4];
        float4 we4 = *(const float4*)(We + lane * 4);
        for (int p = wave; p < P; p += 4) {
            float4 fv = *(const float4*)(fe + ((size_t)b * P + p) * H_ + lane * 4);
            float x0 = fv.x + he4.x; x0 = x0 > 0.f ? x0 : 0.f;
            float x1 = fv.y + he4.y; x1 = x1 > 0.f ? x1 : 0.f;
            float x2 = fv.z + he4.z; x2 = x2 > 0.f ? x2 : 0.f;
            float x3 = fv.w + he4.w; x3 = x3 > 0.f ? x3 : 0.f;
            float s = x0 * we4.x + x1 * we4.y + x2 * we4.z + x3 * we4.w;
            #pragma unroll
            for (int off = 32; off > 0; off >>= 1) s += __shfl_down(s, off);
            if (lane == 0) es[p] = s + be[0];
        }
    }
    __syncthreads();
    {
        float mx = -1e30f;
        for (int p = tid; p < P; p += 256) mx = fmaxf(mx, es[p]);
        #pragma unroll
        for (int off = 32; off > 0; off >>= 1) mx = fmaxf(mx, __shfl_down(mx, off));
        if (lane == 0) red[wave] = mx;
        __syncthreads();
        mx = fmaxf(fmaxf(red[0], red[1]), fmaxf(red[2], red[3]));
        __syncthreads();
        float sum = 0.f;
        for (int p = tid; p < P; p += 256) {
            float ex = expf(es[p] - mx);
            es[p] = ex;
            sum += ex;
        }
        #pragma unroll
        for (int off = 32; off > 0; off >>= 1) sum += __shfl_down(sum, off);
        if (lane == 0) red[wave] = sum;
        __syncthreads();
        sum = red[0] + red[1] + red[2] + red[3];
        float inv = 1.0f / sum;
        for (int p = tid; p < P; p += 256) {
            float wv = es[p] * inv;
            es[p] = wv;
            if (y == 0) out2[((size_t)b * T + t) * P + p] = wv;
        }
    }
    __syncthreads();

    {
        int c4 = tid & 63, q = tid >> 6;
        int src = order[b];
        const float4* f4 = (const float4*)(feat + (size_t)src * P * E) + y * 64 + c4;
        float4 acc = {0.f, 0.f, 0.f, 0.f};
        for (int p = q * 49; p < q * 49 + 49; ++p) {
            float w = es[p];
            float4 fv = f4[(size_t)p * 512];
            acc.x += w * fv.x; acc.y += w * fv.y; acc.z += w * fv.z; acc.w += w * fv.w;
        }
        const float4* g4 = (const float4*)W_gate + y * 64 + c4;
        float4 gacc = {0.f, 0.f, 0.f, 0.f};
        for (int k = q * 64; k < q * 64 + 64; ++k) {
            float hv = hs[k];
            float4 wv = g4[(size_t)k * 512];
            gacc.x += hv * wv.x; gacc.y += hv * wv.y; gacc.z += hv * wv.z; gacc.w += hv * wv.w;
        }
        if (q) { rc[q - 1][c4] = acc; rg[q - 1][c4] = gacc; }
        __syncthreads();
        if (q == 0) {
            #pragma unroll
            for (int j = 0; j < 3; ++j) {
                float4 a = rc[j][c4], g = rg[j][c4];
                acc.x += a.x; acc.y += a.y; acc.z += a.z; acc.w += a.w;
                gacc.x += g.x; gacc.y += g.y; gacc.z += g.z; gacc.w += g.w;
            }
            float4 gb = *(const float4*)(b_gate + (y * 64 + c4) * 4);
            float4 o;
            o.x = acc.x / (1.f + expf(-(gacc.x + gb.x)));
            o.y = acc.y / (1.f + expf(-(gacc.y + gb.y)));
            o.z = acc.z / (1.f + expf(-(gacc.z + gb.z)));
            o.w = acc.w / (1.f + expf(-(gacc.w + gb.w)));
            *(float4*)(xbuf + (size_t)b * KX2 + (y * 64 + c4) * 4) = o;
        }
    }
}

// ---------------- final pointwise only (t == T) ----------------
__global__ __launch_bounds__(256) void pw_final(const int* __restrict__ target,
                                                const float* __restrict__ gpart,
                                                const float* __restrict__ Gemb,
                                                const float* __restrict__ b_ih,
                                                const float* __restrict__ b_hh,
                                                const float* __restrict__ c_rd,
                                                float* __restrict__ hn_all) {
    int b = blockIdx.x;
    if (target[b] < T) return;
    int d = threadIdx.x;
    const float* ge = Gemb + ((size_t)(T - 1) * B + b) * 1024;
    float gi = b_ih[d] + b_hh[d] + ge[d];
    float gf = b_ih[D + d] + b_hh[D + d] + ge[D + d];
    float gg = b_ih[2 * D + d] + b_hh[2 * D + d] + ge[2 * D + d];
    float go = b_ih[3 * D + d] + b_hh[3 * D + d] + ge[3 * D + d];
    #pragma unroll
    for (int ky = 0; ky < NKY; ++ky) {
        const float* gp = gpart + ((size_t)ky * B + b) * 1024;
        gi += gp[d];
        gf += gp[D + d];
        gg += gp[2 * D + d];
        go += gp[3 * D + d];
    }
    float c_old = c_rd[b * D + d];
    float si = 1.f / (1.f + expf(-gi));
    float sf = 1.f / (1.f + expf(-gf));
    float so = 1.f / (1.f + expf(-go));
    float cn = sf * c_old + si * tanhf(gg);
    float hnv = so * tanhf(cn);
    hn_all[((size_t)(T - 1) * B + b) * D + d] = hnv;
}

// ---------------- gate GEMM: K = 2304 split 18-way; grid (16, 18) ----------------
__global__ __launch_bounds__(256) void lstm_gemm(const float* __restrict__ xbuf,
                                                 const float* __restrict__ W_ih,
                                                 const float* __restrict__ W_hh,
                                                 float* __restrict__ gpart) {
    __shared__ float As[32][68];
    __shared__ float Bs[32][64];
    int cb = blockIdx.x;   // 0..15
    int ky = blockIdx.y;   // 0..17
    int tid = threadIdx.x;
    int tx = tid & 15, ty = tid >> 4;
    float acc[4][4] = {};
    int k0base = ky * 128;
    for (int k0 = k0base; k0 < k0base + 128; k0 += 32) {
        #pragma unroll
        for (int q = 0; q < 2; ++q) {
            int idx = q * 256 + tid;
            int kv = idx & 7, m = idx >> 3;
            float4 v = *(const float4*)(xbuf + (size_t)m * KX2 + k0 + kv * 4);
            As[kv * 4 + 0][m] = v.x;
            As[kv * 4 + 1][m] = v.y;
            As[kv * 4 + 2][m] = v.z;
            As[kv * 4 + 3][m] = v.w;
        }
        #pragma unroll
        for (int q = 0; q < 2; ++q) {
            int idx = q * 256 + tid;
            int n4 = idx & 15, kk = idx >> 4;
            int k = k0 + kk;
            const float* src = (k < E) ? (W_ih + (size_t)(EM + k) * 1024)
                                       : (W_hh + (size_t)(k - E) * 1024);
            float4 v = *(const float4*)(src + cb * 64 + n4 * 4);
            *(float4*)&Bs[kk][n4 * 4] = v;
        }
        __syncthreads();
        #pragma unroll
        for (int kk = 0; kk < 32; ++kk) {
            float4 av = *(const float4*)&As[kk][ty * 4];
            float4 bv = *(const float4*)&Bs[kk][tx * 4];
            acc[0][0] += av.x * bv.x; acc[0][1] += av.x * bv.y; acc[0][2] += av.x * bv.z; acc[0][3] += av.x * bv.w;
            acc[1][0] += av.y * bv.x; acc[1][1] += av.y * bv.y; acc[1][2] += av.y * bv.z; acc[1][3] += av.y * bv.w;
            acc[2][0] += av.z * bv.x; acc[2][1] += av.z * bv.y; acc[2][2] += av.z * bv.z; acc[2][3] += av.z * bv.w;
            acc[3][0] += av.w * bv.x; acc[3][1] += av.w * bv.y; acc[3][2] += av.w * bv.z; acc[3][3] += av.w * bv.w;
        }
        __syncthreads();
    }
    #pragma unroll
    for (int a = 0; a < 4; ++a) {
        int bidx = ty * 4 + a;
        float4 o = {acc[a][0], acc[a][1], acc[a][2], acc[a][3]};
        *(float4*)(gpart + ((size_t)ky * B + bidx) * 1024 + cb * 64 + tx * 4) = o;
    }
}

// ---------------- batched head: grid (40, 62); 4 cols x 8 rows per thread, float4 W loads ----------------
__global__ __launch_bounds__(256) void head_batch(const float* __restrict__ hn_all,
                                                  const float* __restrict__ W_head,
                                                  const float* __restrict__ b_head,
                                                  const int* __restrict__ target,
                                                  float* __restrict__ out1) {
    int by = blockIdx.y;
    int t = by >> 1, qh = by & 1;
    int cb = blockIdx.x;                 // 256-col tile; XCD = cb mod 8 (stable -> W_head L2-resident)
    int tid = threadIdx.x;
    int cg = tid & 63;                   // col-quad within tile
    int col = cb * 256 + cg * 4;
    int rgrp = (tid >> 6) * 8;           // 8 rows per thread
    bool colok = (col < V);              // V = 10000 (mult of 4); cb=39 -> only cg<4 active
    if (target[qh * 32] <= t) {          // whole 32-row tile masked: write zeros
        if (colok) {
            float4 z = {0.f, 0.f, 0.f, 0.f};
            #pragma unroll
            for (int r = 0; r < 8; ++r) {
                int brow = qh * 32 + rgrp + r;
                *(float4*)(out1 + ((size_t)brow * T + t) * V + col) = z;
            }
        }
        return;
    }
    __shared__ float hs[32][260];
    #pragma unroll
    for (int q = 0; q < 8; ++q) {
        int idx = q * 256 + tid;
        int r = idx >> 6, kq = idx & 63;
        float4 v = *(const float4*)(hn_all + ((size_t)t * B + qh * 32 + r) * D + kq * 4);
        *(float4*)&hs[r][kq * 4] = v;
    }
    __syncthreads();
    if (!colok) return;                  // no further barriers below
    float4 acc[8] = {};
    const float* wp = W_head + col;
    for (int k = 0; k < D; k += 4) {
        float4 w0 = *(const float4*)(wp + (size_t)k * V);
        float4 w1 = *(const float4*)(wp + (size_t)(k + 1) * V);
        float4 w2 = *(const float4*)(wp + (size_t)(k + 2) * V);
        float4 w3 = *(const float4*)(wp + (size_t)(k + 3) * V);
        #pragma unroll
        for (int r = 0; r < 8; ++r) {
            float4 hv = *(const float4*)&hs[rgrp + r][k];   // broadcast b128
            acc[r].x += hv.x * w0.x + hv.y * w1.x + hv.z * w2.x + hv.w * w3.x;
            acc[r].y += hv.x * w0.y + hv.y * w1.y + hv.z * w2.y + hv.w * w3.y;
            acc[r].z += hv.x * w0.z + hv.y * w1.z + hv.z * w2.z + hv.w * w3.z;
            acc[r].w += hv.x * w0.w + hv.y * w1.w + hv.z * w2.w + hv.w * w3.w;
        }
    }
    float4 bh4 = *(const float4*)(b_head + col);
    #pragma unroll
    for (int r = 0; r < 8; ++r) {
        int brow = qh * 32 + rgrp + r;
        float4 o;
        if (target[brow] > t) {
            o.x = acc[r].x + bh4.x; o.y = acc[r].y + bh4.y;
            o.z = acc[r].z + bh4.z; o.w = acc[r].w + bh4.w;
        } else {
            o.x = 0.f; o.y = 0.f; o.z = 0.f; o.w = 0.f;
        }
        *(float4*)(out1 + ((size_t)brow * T + t) * V + col) = o;
    }
}

extern "C" void kernel_launch(void* const* d_in, const int* in_sizes, int n_in,
                              void* d_out, int out_size, void* d_ws, size_t ws_size,
                              hipStream_t stream) {
    const float* feat   = (const float*)d_in[0];
    const int*   tok    = (const int*)d_in[1];
    const int*   clen   = (const int*)d_in[2];
    const float* Wf     = (const float*)d_in[3];
    const float* bf     = (const float*)d_in[4];
    const float* Wh     = (const float*)d_in[5];
    const float* bh     = (const float*)d_in[6];
    const float* We     = (const float*)d_in[7];
    const float* be     = (const float*)d_in[8];
    const float* emb    = (const float*)d_in[9];
    const float* W_ih   = (const float*)d_in[10];
    const float* b_ih   = (const float*)d_in[11];
    const float* W_hh   = (const float*)d_in[12];
    const float* b_hh   = (const float*)d_in[13];
    const float* W_hid  = (const float*)d_in[14];
    const float* b_hid  = (const float*)d_in[15];
    const float* W_cell = (const float*)d_in[16];
    const float* b_cell = (const float*)d_in[17];
    const float* W_gate = (const float*)d_in[18];
    const float* b_gate = (const float*)d_in[19];
    const float* W_head = (const float*)d_in[20];
    const float* b_head = (const float*)d_in[21];

    float* out1 = (float*)d_out;                       // B*T*V floats (19.84M)
    float* out2 = out1 + (size_t)B * T * V;            // B*T*P floats

    // ---- workspace (~17 MB) ----
    char* wp = (char*)d_ws;
    int* order   = (int*)wp;           wp += 256;
    int* targetp = (int*)wp;           wp += 256;
    float* fe    = (float*)wp;         wp += (size_t)B * P * H_ * sizeof(float);
    float* hbuf  = (float*)wp;         wp += (size_t)B * D * sizeof(float);
    float* cbuf  = (float*)wp;         wp += (size_t)2 * B * D * sizeof(float);
    float* xbuf  = (float*)wp;         wp += (size_t)B * KX2 * sizeof(float);
    float* mean_feat = (float*)wp;     wp += (size_t)B * E * sizeof(float);
    float* hpart = (float*)wp;         wp += (size_t)8 * B * 512 * sizeof(float);
    float* hn_all = (float*)wp;        wp += (size_t)T * B * D * sizeof(float);

    // ---- transient scratch inside out1 (fully overwritten by head_batch at the end) ----
    float* fepart = out1;                               // 4 * FEPART_SZ = 12.85M floats
    float* Gemb   = out1 + 4 * FEPART_SZ;               // T*B*1024 = 2.03M floats
    float* gpart  = Gemb + (size_t)T * B * 1024;        // NKY*B*1024 = 1.18M (total 16.06M < 19.84M)

    hipMemsetAsync(out2, 0, (size_t)B * T * P * sizeof(float), stream);

    sort_kernel<<<1, 64, 0, stream>>>(clen, order, targetp);
    mean_kernel<<<dim3(B, E / 256), 256, 0, stream>>>(feat, order, mean_feat);
    h0c0_gemm<<<dim3(8, 8), 256, 0, stream>>>(mean_feat, W_hid, W_cell, hpart);
    h0c0_reduce<<<B, 256, 0, stream>>>(hpart, b_hid, b_cell, hbuf, cbuf, xbuf);
    fe_gemm<<<dim3(196, 4, 4), 256, 0, stream>>>(feat, order, Wf, fepart);
    fe_reduce<<<3136, 256, 0, stream>>>(fe, fepart, bf);
    gemb_gemm<<<dim3(16, T), 256, 0, stream>>>(emb, tok, order, W_ih, Gemb);

    for (int t = 0; t < T; ++t) {
        attn_ctx<<<dim3(B, 8), 256, 0, stream>>>(targetp, gpart, Gemb, b_ih, b_hh,
                                                 order, Wh, bh, We, be, fe, hbuf,
                                                 cbuf + (size_t)((t + 1) & 1) * B * D,
                                                 cbuf + (size_t)(t & 1) * B * D,
                                                 hn_all, xbuf, out2,
                                                 feat, W_gate, b_gate, t);
        lstm_gemm<<<dim3(16, NKY), 256, 0, stream>>>(xbuf, W_ih, W_hh, gpart);
    }
    pw_final<<<B, 256, 0, stream>>>(targetp, gpart, Gemb, b_ih, b_hh, cbuf, hn_all);

    // head writes every (b,t,col) exactly once (zeros for masked) -> no out1 memset needed
    head_batch<<<dim3(40, 62), 256, 0, stream>>>(hn_all, W_head, b_head, targetp, out1);
}